// Round 12
// baseline (2603.500 us; speedup 1.0000x reference)
//
#include <hip/hip_runtime.h>
#include <hip/hip_bf16.h>

#define NN 20000
#define NE 320000
#define TOUT 12
#define DEGMAX 96
#define SGXP 1028   // sgx row stride (bf16): quads hit disjoint bank groups

typedef __bf16 bf16x8 __attribute__((ext_vector_type(8)));
typedef float float4v __attribute__((ext_vector_type(4)));

#define LD8(p) (*(const bf16x8*)(p))
#define MFMA16(a,b,c) __builtin_amdgcn_mfma_f32_16x16x32_bf16((a),(b),(c),0,0,0)

__device__ __forceinline__ float bf2f(const __hip_bfloat16 v){ return __bfloat162float(v); }
__device__ __forceinline__ __hip_bfloat16 f2bf(float v){ return __float2bfloat16(v); }
__device__ __forceinline__ float sigmoidf_(float x){ return 1.0f/(1.0f + __expf(-x)); }
// branch-free tanh via expf: correct saturation at +/-inf, fine for 2% tolerance
__device__ __forceinline__ float tanhf_(float x){ float e = __expf(2.f*x); return 1.f - 2.f/(e + 1.f); }
__device__ __forceinline__ float rdf(const void* p, int i, int f32){
  return f32 ? ((const float*)p)[i] : __bfloat162float(((const __hip_bfloat16*)p)[i]);
}

// ---------------- input dtype detector ----------------
__global__ void k_detect(const void* xraw, int* flag){
  __shared__ int cnt;
  if(threadIdx.x == 0) cnt = 0;
  __syncthreads();
  const unsigned* w = (const unsigned*)xraw;
  int local = 0;
  for(int i = threadIdx.x; i < 4096; i += 256){
    unsigned b = (w[i] >> 8) & 0x7F;
    if(b >= 0x33 && b <= 0x3F) local++;
  }
  atomicAdd(&cnt, local);
  __syncthreads();
  if(threadIdx.x == 0) *flag = (cnt > 2048) ? 0 : 1;   // 1 => fp32 inputs
}

// guard signature: constant 256.0 everywhere (fp32 out)
__global__ void k_fail(float* out, int n){
  int i = blockIdx.x*256 + threadIdx.x;
  if(i < n) out[i] = 256.0f;
}

// ---------------- CSR build ----------------
__global__ void k_count(const int* __restrict__ dst, int* __restrict__ deg){
  int e = blockIdx.x*256 + threadIdx.x;
  if(e < NE){
    unsigned d = (unsigned)dst[e];
    if(d < NN) atomicAdd(&deg[d], 1);
  }
}

__global__ void k_scan(const int* __restrict__ deg, int* __restrict__ offp, int* __restrict__ cursor){
  __shared__ int part[256];
  __shared__ int excl[257];
  const int CH = (NN + 255)/256;
  int tid = threadIdx.x;
  int lo = tid*CH;
  int hi = lo + CH; if(hi > NN) hi = NN;
  int s = 0;
  for(int i=lo;i<hi;i++) s += deg[i];
  part[tid] = s;
  __syncthreads();
  if(tid == 0){
    int run = 0;
    for(int i=0;i<256;i++){ excl[i] = run; run += part[i]; }
    excl[256] = run;
  }
  __syncthreads();
  int run = excl[tid];
  for(int i=lo;i<hi;i++){ offp[i] = run; cursor[i] = run; run += deg[i]; }
  if(tid == 0) offp[NN] = excl[256];
}

__global__ void k_fill(const int* __restrict__ src, const int* __restrict__ dst,
                       int* __restrict__ cursor, int* __restrict__ csr_src){
  int e = blockIdx.x*256 + threadIdx.x;
  if(e >= NE) return;
  unsigned d = (unsigned)dst[e];
  if(d >= NN) return;
  unsigned p = (unsigned)atomicAdd(&cursor[d], 1);
  if(p < NE){
    unsigned sv = (unsigned)src[e];
    csr_src[p] = (sv < NN) ? (int)sv : 0;
  }
}

// ---------------- conversions / weight prep ----------------
__global__ void k_cvt_x(const void* __restrict__ x, const int* __restrict__ flag,
                        __hip_bfloat16* __restrict__ xb){
  int i = blockIdx.x*256 + threadIdx.x;
  int f = *flag;
  if(i < NN*256) xb[i] = f2bf(rdf(x, i, f));
}

__global__ void k_prep(const void* __restrict__ w_src, const void* __restrict__ w_dst,
                       const void* __restrict__ w_hh, const int* __restrict__ flag,
                       __hip_bfloat16* __restrict__ wsrcT, __hip_bfloat16* __restrict__ wdstT,
                       __hip_bfloat16* __restrict__ whhb){
  int tid = blockIdx.x*256 + threadIdx.x;
  int f = *flag;
  if(tid < 131072){
    int l = tid >> 16, r = tid & 65535, o = r >> 8, i = r & 255;
    wsrcT[tid] = f2bf(rdf(w_src, l*65536 + i*256 + o, f));
    wdstT[tid] = f2bf(rdf(w_dst, l*65536 + i*256 + o, f));
  }
  if(tid < 262144) whhb[tid] = f2bf(rdf(w_hh, tid, f));
}

// Wc[g,k] = sum_j Wih[g,j] * mlp_w[j, 1+k]
__global__ void k_prep_wc(const void* __restrict__ wih, const void* __restrict__ mlp_w,
                          const int* __restrict__ flag, __hip_bfloat16* __restrict__ Wc){
  int g = blockIdx.x;
  int k = threadIdx.x;
  int f = *flag;
  float s = 0.f;
  for(int j=0;j<256;j++) s += rdf(wih, g*256+j, f) * rdf(mlp_w, j*257 + 1 + k, f);
  Wc[g*256+k] = f2bf(s);
}

__global__ void k_prep_small(const void* __restrict__ wih, const void* __restrict__ mlp_w,
                             const void* __restrict__ mlp_b,
                             const void* __restrict__ b_ih, const void* __restrict__ b_hh,
                             const void* __restrict__ att, const void* __restrict__ gbias,
                             const void* __restrict__ init_w, const void* __restrict__ init_b,
                             const void* __restrict__ out_w, const void* __restrict__ out_b,
                             const int* __restrict__ flag,
                             float* __restrict__ u, float* __restrict__ bc,
                             float* __restrict__ attf, float* __restrict__ gbiasf,
                             float* __restrict__ initwf, float* __restrict__ outwf,
                             float* __restrict__ sc){
  int g = blockIdx.x*256 + threadIdx.x;
  int f = *flag;
  if(g < 1024){
    float su = 0.f, sb = 0.f;
    for(int j=0;j<256;j++){
      float w = rdf(wih, g*256+j, f);
      su += w * rdf(mlp_w, j*257, f);
      sb += w * rdf(mlp_b, j, f);
    }
    u[g] = su;
    bc[g] = sb + rdf(b_ih, g, f) + rdf(b_hh, g, f);
  }
  if(g < 512){ attf[g] = rdf(att, g, f); gbiasf[g] = rdf(gbias, g, f); }
  if(g < 256){ initwf[g] = rdf(init_w, g, f); outwf[g] = rdf(out_w, g, f); }
  if(g == 0){ sc[0] = rdf(init_b, 0, f); sc[1] = rdf(out_b, 0, f); }
}

// ---------------- NT GEMM (out-of-place): Q[m,n] = sum_k P[m,k]*B[n,k] ----------------
__global__ __launch_bounds__(256) void k_gemm_nt_bf(const __hip_bfloat16* __restrict__ A,
                                                    const __hip_bfloat16* __restrict__ B,
                                                    __hip_bfloat16* __restrict__ Cb){
  int wave = threadIdx.x >> 6;
  int lane = threadIdx.x & 63;
  int l16 = lane & 15, quad = lane >> 4, quad8 = quad*8;
  int mBase = blockIdx.x*64 + wave*16;
  int nBase = blockIdx.y*64;
  int arow = mBase + l16; if(arow >= NN) arow = NN-1;
  const __hip_bfloat16* aptr = A + (size_t)arow*256 + quad8;
  float4v acc[4];
  #pragma unroll
  for(int nt=0;nt<4;nt++){ acc[nt][0]=0.f; acc[nt][1]=0.f; acc[nt][2]=0.f; acc[nt][3]=0.f; }
  for(int k0=0;k0<256;k0+=32){
    bf16x8 a = LD8(aptr + k0);
    #pragma unroll
    for(int nt=0;nt<4;nt++){
      const __hip_bfloat16* bptr = B + (size_t)(nBase + nt*16 + l16)*256 + k0 + quad8;
      acc[nt] = MFMA16(a, LD8(bptr), acc[nt]);
    }
  }
  #pragma unroll
  for(int nt=0;nt<4;nt++){
    int col = nBase + nt*16 + l16;
    #pragma unroll
    for(int r=0;r<4;r++){
      int row = mBase + quad*4 + r;
      if(row < NN) Cb[(size_t)row*256 + col] = f2bf(acc[nt][r]);
    }
  }
}

// ---------------- in-place NT GEMM: P = P@B^T (LDS-staged A; row-exclusive blocks) ----
__global__ __launch_bounds__(256) void k_gemm_inplace(__hip_bfloat16* __restrict__ P,
                                                      const __hip_bfloat16* __restrict__ B){
  __shared__ __hip_bfloat16 sA[64*264];
  int tid = threadIdx.x;
  int mBase = blockIdx.x*64;
  {
    int r = tid >> 2;
    int c0 = (tid & 3)*64;
    int grow = mBase + r; if(grow >= NN) grow = NN-1;
    const __hip_bfloat16* srcp = P + (size_t)grow*256 + c0;
    #pragma unroll
    for(int j=0;j<8;j++) *(bf16x8*)(&sA[r*264 + c0 + j*8]) = LD8(srcp + j*8);
  }
  __syncthreads();
  int w = tid>>6, lane = tid&63, l16 = lane&15, quad = lane>>4, quad8 = quad*8;
  const __hip_bfloat16* arow = &sA[(w*16 + l16)*264 + quad8];
  float4v acc[16];
  #pragma unroll
  for(int nt=0;nt<16;nt++){ acc[nt][0]=0.f; acc[nt][1]=0.f; acc[nt][2]=0.f; acc[nt][3]=0.f; }
  for(int k0=0;k0<256;k0+=32){
    bf16x8 a = *(const bf16x8*)(arow + k0);
    #pragma unroll
    for(int nt=0;nt<16;nt++)
      acc[nt] = MFMA16(a, LD8(B + (size_t)(nt*16+l16)*256 + k0 + quad8), acc[nt]);
  }
  #pragma unroll
  for(int nt=0;nt<16;nt++){
    int col = nt*16 + l16;
    #pragma unroll
    for(int r=0;r<4;r++){
      int row = mBase + w*16 + quad*4 + r;
      if(row < NN) P[(size_t)row*256 + col] = f2bf(acc[nt][r]);
    }
  }
}

// ---------------- fused GAT edge phase: logits+softmax+aggregate+ELU (per node) ------
__global__ __launch_bounds__(256) void k_node_fused(const __hip_bfloat16* __restrict__ Q,
                                                    __hip_bfloat16* __restrict__ P,
                                                    const int* __restrict__ offp,
                                                    const int* __restrict__ csr_src,
                                                    const float* __restrict__ attf,
                                                    const float* __restrict__ gbiasf){
  __shared__ float slog[DEGMAX*4];
  __shared__ int ssrc[DEGMAX];
  int node = blockIdx.x;
  int tid = threadIdx.x;
  int s0 = offp[node], s1 = offp[node+1];
  if(s0 < 0) s0 = 0; if(s0 > NE) s0 = NE;
  if(s1 < s0) s1 = s0; if(s1 > NE) s1 = NE;
  int deg = s1 - s0; if(deg > DEGMAX) deg = DEGMAX;
  if(tid < deg){
    unsigned sv = (unsigned)csr_src[s0 + tid];
    ssrc[tid] = (sv < NN) ? (int)sv : 0;
  }
  __syncthreads();
  int w = tid>>6, lane = tid&63;
  for(int idx=w; idx<deg; idx+=4){
    const __hip_bfloat16* pl = Q + (size_t)ssrc[idx]*256;
    const __hip_bfloat16* pr = P + (size_t)node*256;
    float a[4];
    #pragma unroll
    for(int h=0;h<4;h++){
      float v = bf2f(pl[h*64+lane]) + bf2f(pr[h*64+lane]);
      v = (v > 0.f) ? v : 0.2f*v;
      a[h] = v * attf[h*64+lane];
    }
    #pragma unroll
    for(int h=0;h<4;h++){
      float s = a[h];
      s += __shfl_xor(s, 1, 64);
      s += __shfl_xor(s, 2, 64);
      s += __shfl_xor(s, 4, 64);
      s += __shfl_xor(s, 8, 64);
      s += __shfl_xor(s, 16, 64);
      s += __shfl_xor(s, 32, 64);
      if(lane == 0) slog[idx*4 + h] = s;
    }
  }
  __syncthreads();
  if(tid < 4){
    int h = tid;
    float m = -1e30f;
    for(int i=0;i<deg;i++) m = fmaxf(m, slog[i*4+h]);
    float den = 0.f;
    for(int i=0;i<deg;i++) den += __expf(slog[i*4+h] - m);
    float inv = (den > 0.f) ? 1.f/den : 0.f;
    for(int i=0;i<deg;i++) slog[i*4+h] = __expf(slog[i*4+h] - m)*inv;
  }
  __syncthreads();
  int d = tid, h = d>>6;
  float acc = 0.f;
  for(int i=0;i<deg;i++) acc += slog[i*4+h] * bf2f(Q[(size_t)ssrc[i]*256 + d]);
  acc += gbiasf[d];
  acc = (acc > 0.f) ? acc : (__expf(acc) - 1.f);   // ELU
  P[(size_t)node*256 + d] = f2bf(acc);
}

// ---------------- persistent LSTM: 512 threads (8 waves), 16 rows/block --------------
// Wave w owns cols [w*32,(w+1)*32) for ALL 4 gates -> nt = g*2+tc, acc = 8 tiles
// (32 AGPR/thread). Per-thread state ~100 regs << (512,6) cap (~341) -> no spill.
// LDS ~43 KB -> 3 blocks/CU = 24 waves/CU. GX in LDS; Whh re-read per step from L2.
__global__ __launch_bounds__(512, 6) void k_lstm12(const __hip_bfloat16* __restrict__ ctx,
                                                   const __hip_bfloat16* __restrict__ Wc,
                                                   const __hip_bfloat16* __restrict__ Whh,
                                                   const float* __restrict__ u_vec,
                                                   const float* __restrict__ bc_vec,
                                                   const float* __restrict__ initwf,
                                                   const float* __restrict__ outwf,
                                                   const float* __restrict__ sc,
                                                   float* __restrict__ out){
  __shared__ __hip_bfloat16 sgx[16*SGXP];    // 32.9KB: GX+bc, [row][gatecol]
  __shared__ __hip_bfloat16 sh[16*264];      // h tile (bank-padded)
  __shared__ float spart[512];               // init-reduction scratch
  __shared__ float spartw[128];              // per-wave out-projection partials
  __shared__ float sprev[16];
  int tid = threadIdx.x;
  int mBase = blockIdx.x*16;                 // 1250*16 == NN exactly
  int w = tid>>6, lane = tid&63, l16 = lane&15, quad = lane>>4, quad8 = quad*8;
  // h0 = ctx rows (512 threads: 16 rows x 32 chunks of 8)
  {
    int r = tid >> 5, c0 = (tid & 31)*8;
    *(bf16x8*)(&sh[r*264 + c0]) = LD8(ctx + (size_t)(mBase + r)*256 + c0);
  }
  __syncthreads();
  // prev0 = ctx @ init_w + init_b
  {
    int r = tid >> 5, c0 = (tid & 31)*8;
    float part = 0.f;
    #pragma unroll
    for(int j=0;j<8;j++) part += bf2f(sh[r*264 + c0 + j]) * initwf[c0 + j];
    spart[tid] = part;
  }
  __syncthreads();
  if(tid < 16){
    float s = 0.f;
    #pragma unroll
    for(int j=0;j<32;j++) s += spart[tid*32 + j];
    sprev[tid] = s + sc[0];
  }
  // per-thread constants: this wave's 32-col slab, 4 gates
  float ureg[8], owreg[2];
  #pragma unroll
  for(int g=0;g<4;g++)
    #pragma unroll
    for(int tc=0;tc<2;tc++) ureg[g*2+tc] = u_vec[g*256 + w*32 + tc*16 + l16];
  #pragma unroll
  for(int tc=0;tc<2;tc++) owreg[tc] = outwf[w*32 + tc*16 + l16];
  float outb = sc[1];
  // GX phase: acc = ctx@Wc^T (4 gates x 32 cols), +bc -> sgx
  {
    float4v acc[8];
    #pragma unroll
    for(int nt=0;nt<8;nt++){ acc[nt][0]=0.f; acc[nt][1]=0.f; acc[nt][2]=0.f; acc[nt][3]=0.f; }
    for(int k0=0;k0<256;k0+=32){
      bf16x8 a = *(const bf16x8*)(&sh[l16*264 + k0 + quad8]);
      #pragma unroll
      for(int nt=0;nt<8;nt++){
        int brow = (nt>>1)*256 + w*32 + (nt&1)*16 + l16;
        acc[nt] = MFMA16(a, LD8(Wc + (size_t)brow*256 + k0 + quad8), acc[nt]);
      }
    }
    #pragma unroll
    for(int nt=0;nt<8;nt++){
      int gc = (nt>>1)*256 + w*32 + (nt&1)*16 + l16;
      float bcv = bc_vec[gc];
      #pragma unroll
      for(int r=0;r<4;r++)
        sgx[(quad*4 + r)*SGXP + gc] = f2bf(acc[nt][r] + bcv);
    }
  }
  __syncthreads();   // sgx + sprev visible
  float creg[8];
  #pragma unroll
  for(int i=0;i<8;i++) creg[i] = 0.f;
  for(int step=0; step<TOUT; step++){
    // (a) gates GEMM: acc[g*2+tc] = h @ Whh^T slab
    float4v acc[8];
    #pragma unroll
    for(int nt=0;nt<8;nt++){ acc[nt][0]=0.f; acc[nt][1]=0.f; acc[nt][2]=0.f; acc[nt][3]=0.f; }
    for(int k0=0;k0<256;k0+=32){
      bf16x8 a = *(const bf16x8*)(&sh[l16*264 + k0 + quad8]);
      #pragma unroll
      for(int nt=0;nt<8;nt++){
        int brow = (nt>>1)*256 + w*32 + (nt&1)*16 + l16;
        acc[nt] = MFMA16(a, LD8(Whh + (size_t)brow*256 + k0 + quad8), acc[nt]);
      }
    }
    __syncthreads();   // S1: all sh reads done; sprev (from prev step) visible
    // (b) in-register activation + h write + out-projection partials
    float hsum[4] = {0.f, 0.f, 0.f, 0.f};
    #pragma unroll
    for(int tc=0;tc<2;tc++){
      int col = w*32 + tc*16 + l16;
      #pragma unroll
      for(int r=0;r<4;r++){
        int row = quad*4 + r;
        float p = sprev[row];
        float g0 = acc[tc][r]     + bf2f(sgx[row*SGXP + col])       + p*ureg[tc];
        float g1 = acc[2+tc][r]   + bf2f(sgx[row*SGXP + 256 + col]) + p*ureg[2+tc];
        float g2 = acc[4+tc][r]   + bf2f(sgx[row*SGXP + 512 + col]) + p*ureg[4+tc];
        float g3 = acc[6+tc][r]   + bf2f(sgx[row*SGXP + 768 + col]) + p*ureg[6+tc];
        float iv = sigmoidf_(g0), fv = sigmoidf_(g1);
        float gv = tanhf_(g2),    ov = sigmoidf_(g3);
        float cn = fv*creg[tc*4+r] + iv*gv;
        creg[tc*4+r] = cn;
        float hn = ov * tanhf_(cn);
        sh[row*264 + col] = f2bf(hn);
        hsum[r] += hn * owreg[tc];
      }
    }
    #pragma unroll
    for(int r=0;r<4;r++){
      hsum[r] += __shfl_xor(hsum[r], 1, 64);
      hsum[r] += __shfl_xor(hsum[r], 2, 64);
      hsum[r] += __shfl_xor(hsum[r], 4, 64);
      hsum[r] += __shfl_xor(hsum[r], 8, 64);
    }
    if(l16 == 0){
      #pragma unroll
      for(int r=0;r<4;r++) spartw[w*16 + quad*4 + r] = hsum[r];
    }
    __syncthreads();   // S2: sh writes + spartw visible
    if(tid < 16){
      float s = outb;
      #pragma unroll
      for(int ww=0;ww<8;ww++) s += spartw[ww*16 + tid];
      sprev[tid] = s;
      out[(size_t)(mBase + tid)*TOUT + step] = s;
    }
    // next S1 makes sprev visible before next activation
  }
}

// ---------------- launch ----------------
extern "C" void kernel_launch(void* const* d_in, const int* in_sizes, int n_in,
                              void* d_out, int out_size, void* d_ws, size_t ws_size,
                              hipStream_t stream){
  const void* x      = d_in[0];
  const int*  ei     = (const int*)d_in[1];
  const void* w_src  = d_in[2];
  const void* w_dst  = d_in[3];
  const void* att    = d_in[4];
  const void* gbias  = d_in[5];
  const void* mlp_w  = d_in[6];
  const void* mlp_b  = d_in[7];
  const void* w_ih   = d_in[8];
  const void* w_hh   = d_in[9];
  const void* b_ih   = d_in[10];
  const void* b_hh   = d_in[11];
  const void* init_w = d_in[12];
  const void* init_b = d_in[13];
  const void* out_w  = d_in[14];
  const void* out_b  = d_in[15];
  float* out = (float*)d_out;
  const int* srcp = ei;
  const int* dstp = ei + NE;
  (void)in_sizes; (void)n_in;

  char* ws = (char*)d_ws;
  size_t off = 0;
  auto alloc = [&](size_t bytes)->void*{
    void* p = ws + off;
    off += (bytes + 255) & ~(size_t)255;
    return p;
  };
  __hip_bfloat16* P = (__hip_bfloat16*)alloc((size_t)NN*256*2);  // x -> xr -> layer out -> ctx
  __hip_bfloat16* Q = (__hip_bfloat16*)alloc((size_t)NN*256*2);  // xl per layer
  int* deg      = (int*)alloc((size_t)NN*4);
  int* offp     = (int*)alloc((size_t)(NN+1)*4);
  int* cursor   = (int*)alloc((size_t)NN*4);
  int* csr_src  = (int*)alloc((size_t)NE*4);
  __hip_bfloat16* wsrcT = (__hip_bfloat16*)alloc((size_t)131072*2);
  __hip_bfloat16* wdstT = (__hip_bfloat16*)alloc((size_t)131072*2);
  __hip_bfloat16* whhb  = (__hip_bfloat16*)alloc((size_t)262144*2);
  __hip_bfloat16* Wc    = (__hip_bfloat16*)alloc((size_t)262144*2);
  float* u_vec  = (float*)alloc(1024*4);
  float* bc_vec = (float*)alloc(1024*4);
  float* attf   = (float*)alloc(512*4);
  float* gbiasf = (float*)alloc(512*4);
  float* initwf = (float*)alloc(256*4);
  float* outwf  = (float*)alloc(256*4);
  float* sc     = (float*)alloc(2*4);
  int*   flag   = (int*)alloc(4);
  // total ~23.6 MB

  if(off > ws_size){
    k_fail<<<(out_size + 255)/256, 256, 0, stream>>>(out, out_size);
    return;
  }

  // dtype detect + CSR + prep
  k_detect<<<1, 256, 0, stream>>>(x, flag);
  hipMemsetAsync(deg, 0, (size_t)NN*4, stream);
  hipMemsetAsync(csr_src, 0xFF, (size_t)NE*4, stream);
  k_count<<<NE/256, 256, 0, stream>>>(dstp, deg);
  k_scan<<<1, 256, 0, stream>>>(deg, offp, cursor);
  k_fill<<<NE/256, 256, 0, stream>>>(srcp, dstp, cursor, csr_src);
  k_cvt_x<<<NN, 256, 0, stream>>>(x, flag, P);
  k_prep<<<1024, 256, 0, stream>>>(w_src, w_dst, w_hh, flag, wsrcT, wdstT, whhb);
  k_prep_wc<<<1024, 256, 0, stream>>>(w_ih, mlp_w, flag, Wc);
  k_prep_small<<<4, 256, 0, stream>>>(w_ih, mlp_w, mlp_b, b_ih, b_hh, att, gbias,
                                      init_w, init_b, out_w, out_b, flag,
                                      u_vec, bc_vec, attf, gbiasf, initwf, outwf, sc);

  // GAT layers: Q = P@Wsrc^T (xl); P = P@Wdst^T in-place (xr); fused edge phase -> P
  dim3 g64(313, 4);
  for(int l=0;l<2;l++){
    k_gemm_nt_bf<<<g64, 256, 0, stream>>>(P, wsrcT + l*65536, Q);
    k_gemm_inplace<<<313, 256, 0, stream>>>(P, wdstT + l*65536);
    k_node_fused<<<NN, 256, 0, stream>>>(Q, P, offp, csr_src, attf + l*256, gbiasf + l*256);
  }

  // persistent LSTM decoder: 512-thread blocks, 8-tile acc, no spills
  k_lstm12<<<1250, 512, 0, stream>>>(P, Wc, whhb, u_vec, bc_vec, initwf, outwf, sc, out);
}

// Round 13
// 1746.881 us; speedup vs baseline: 1.4904x; 1.4904x over previous
//
#include <hip/hip_runtime.h>
#include <hip/hip_bf16.h>

#define NN 20000
#define NE 320000
#define TOUT 12
#define DEGMAX 96
#define SGXP 1028   // sgx row stride (bf16): quads hit disjoint bank groups

typedef __bf16 bf16x8 __attribute__((ext_vector_type(8)));
typedef float float4v __attribute__((ext_vector_type(4)));

#define LD8(p) (*(const bf16x8*)(p))
#define MFMA16(a,b,c) __builtin_amdgcn_mfma_f32_16x16x32_bf16((a),(b),(c),0,0,0)

__device__ __forceinline__ float bf2f(const __hip_bfloat16 v){ return __bfloat162float(v); }
__device__ __forceinline__ __hip_bfloat16 f2bf(float v){ return __float2bfloat16(v); }
__device__ __forceinline__ float sigmoidf_(float x){ return 1.0f/(1.0f + __expf(-x)); }
// branch-free tanh via expf: correct saturation at +/-inf, fine for 2% tolerance
__device__ __forceinline__ float tanhf_(float x){ float e = __expf(2.f*x); return 1.f - 2.f/(e + 1.f); }
__device__ __forceinline__ float rdf(const void* p, int i, int f32){
  return f32 ? ((const float*)p)[i] : __bfloat162float(((const __hip_bfloat16*)p)[i]);
}

// ---------------- input dtype detector ----------------
__global__ void k_detect(const void* xraw, int* flag){
  __shared__ int cnt;
  if(threadIdx.x == 0) cnt = 0;
  __syncthreads();
  const unsigned* w = (const unsigned*)xraw;
  int local = 0;
  for(int i = threadIdx.x; i < 4096; i += 256){
    unsigned b = (w[i] >> 8) & 0x7F;
    if(b >= 0x33 && b <= 0x3F) local++;
  }
  atomicAdd(&cnt, local);
  __syncthreads();
  if(threadIdx.x == 0) *flag = (cnt > 2048) ? 0 : 1;   // 1 => fp32 inputs
}

// guard signature: constant 256.0 everywhere (fp32 out)
__global__ void k_fail(float* out, int n){
  int i = blockIdx.x*256 + threadIdx.x;
  if(i < n) out[i] = 256.0f;
}

// ---------------- CSR build ----------------
__global__ void k_count(const int* __restrict__ dst, int* __restrict__ deg){
  int e = blockIdx.x*256 + threadIdx.x;
  if(e < NE){
    unsigned d = (unsigned)dst[e];
    if(d < NN) atomicAdd(&deg[d], 1);
  }
}

__global__ void k_scan(const int* __restrict__ deg, int* __restrict__ offp, int* __restrict__ cursor){
  __shared__ int part[256];
  __shared__ int excl[257];
  const int CH = (NN + 255)/256;
  int tid = threadIdx.x;
  int lo = tid*CH;
  int hi = lo + CH; if(hi > NN) hi = NN;
  int s = 0;
  for(int i=lo;i<hi;i++) s += deg[i];
  part[tid] = s;
  __syncthreads();
  if(tid == 0){
    int run = 0;
    for(int i=0;i<256;i++){ excl[i] = run; run += part[i]; }
    excl[256] = run;
  }
  __syncthreads();
  int run = excl[tid];
  for(int i=lo;i<hi;i++){ offp[i] = run; cursor[i] = run; run += deg[i]; }
  if(tid == 0) offp[NN] = excl[256];
}

__global__ void k_fill(const int* __restrict__ src, const int* __restrict__ dst,
                       int* __restrict__ cursor, int* __restrict__ csr_src){
  int e = blockIdx.x*256 + threadIdx.x;
  if(e >= NE) return;
  unsigned d = (unsigned)dst[e];
  if(d >= NN) return;
  unsigned p = (unsigned)atomicAdd(&cursor[d], 1);
  if(p < NE){
    unsigned sv = (unsigned)src[e];
    csr_src[p] = (sv < NN) ? (int)sv : 0;
  }
}

// ---------------- conversions / weight prep ----------------
__global__ void k_cvt_x(const void* __restrict__ x, const int* __restrict__ flag,
                        __hip_bfloat16* __restrict__ xb){
  int i = blockIdx.x*256 + threadIdx.x;
  int f = *flag;
  if(i < NN*256) xb[i] = f2bf(rdf(x, i, f));
}

__global__ void k_prep(const void* __restrict__ w_src, const void* __restrict__ w_dst,
                       const void* __restrict__ w_hh, const int* __restrict__ flag,
                       __hip_bfloat16* __restrict__ wsrcT, __hip_bfloat16* __restrict__ wdstT,
                       __hip_bfloat16* __restrict__ whhb){
  int tid = blockIdx.x*256 + threadIdx.x;
  int f = *flag;
  if(tid < 131072){
    int l = tid >> 16, r = tid & 65535, o = r >> 8, i = r & 255;
    wsrcT[tid] = f2bf(rdf(w_src, l*65536 + i*256 + o, f));
    wdstT[tid] = f2bf(rdf(w_dst, l*65536 + i*256 + o, f));
  }
  if(tid < 262144) whhb[tid] = f2bf(rdf(w_hh, tid, f));
}

// Wc[g,k] = sum_j Wih[g,j] * mlp_w[j, 1+k]
__global__ void k_prep_wc(const void* __restrict__ wih, const void* __restrict__ mlp_w,
                          const int* __restrict__ flag, __hip_bfloat16* __restrict__ Wc){
  int g = blockIdx.x;
  int k = threadIdx.x;
  int f = *flag;
  float s = 0.f;
  for(int j=0;j<256;j++) s += rdf(wih, g*256+j, f) * rdf(mlp_w, j*257 + 1 + k, f);
  Wc[g*256+k] = f2bf(s);
}

__global__ void k_prep_small(const void* __restrict__ wih, const void* __restrict__ mlp_w,
                             const void* __restrict__ mlp_b,
                             const void* __restrict__ b_ih, const void* __restrict__ b_hh,
                             const void* __restrict__ att, const void* __restrict__ gbias,
                             const void* __restrict__ init_w, const void* __restrict__ init_b,
                             const void* __restrict__ out_w, const void* __restrict__ out_b,
                             const int* __restrict__ flag,
                             float* __restrict__ u, float* __restrict__ bc,
                             float* __restrict__ attf, float* __restrict__ gbiasf,
                             float* __restrict__ initwf, float* __restrict__ outwf,
                             float* __restrict__ sc){
  int g = blockIdx.x*256 + threadIdx.x;
  int f = *flag;
  if(g < 1024){
    float su = 0.f, sb = 0.f;
    for(int j=0;j<256;j++){
      float w = rdf(wih, g*256+j, f);
      su += w * rdf(mlp_w, j*257, f);
      sb += w * rdf(mlp_b, j, f);
    }
    u[g] = su;
    bc[g] = sb + rdf(b_ih, g, f) + rdf(b_hh, g, f);
  }
  if(g < 512){ attf[g] = rdf(att, g, f); gbiasf[g] = rdf(gbias, g, f); }
  if(g < 256){ initwf[g] = rdf(init_w, g, f); outwf[g] = rdf(out_w, g, f); }
  if(g == 0){ sc[0] = rdf(init_b, 0, f); sc[1] = rdf(out_b, 0, f); }
}

// ---------------- NT GEMM (out-of-place): Q[m,n] = sum_k P[m,k]*B[n,k] ----------------
__global__ __launch_bounds__(256) void k_gemm_nt_bf(const __hip_bfloat16* __restrict__ A,
                                                    const __hip_bfloat16* __restrict__ B,
                                                    __hip_bfloat16* __restrict__ Cb){
  int wave = threadIdx.x >> 6;
  int lane = threadIdx.x & 63;
  int l16 = lane & 15, quad = lane >> 4, quad8 = quad*8;
  int mBase = blockIdx.x*64 + wave*16;
  int nBase = blockIdx.y*64;
  int arow = mBase + l16; if(arow >= NN) arow = NN-1;
  const __hip_bfloat16* aptr = A + (size_t)arow*256 + quad8;
  float4v acc[4];
  #pragma unroll
  for(int nt=0;nt<4;nt++){ acc[nt][0]=0.f; acc[nt][1]=0.f; acc[nt][2]=0.f; acc[nt][3]=0.f; }
  for(int k0=0;k0<256;k0+=32){
    bf16x8 a = LD8(aptr + k0);
    #pragma unroll
    for(int nt=0;nt<4;nt++){
      const __hip_bfloat16* bptr = B + (size_t)(nBase + nt*16 + l16)*256 + k0 + quad8;
      acc[nt] = MFMA16(a, LD8(bptr), acc[nt]);
    }
  }
  #pragma unroll
  for(int nt=0;nt<4;nt++){
    int col = nBase + nt*16 + l16;
    #pragma unroll
    for(int r=0;r<4;r++){
      int row = mBase + quad*4 + r;
      if(row < NN) Cb[(size_t)row*256 + col] = f2bf(acc[nt][r]);
    }
  }
}

// ---------------- in-place NT GEMM: P = P@B^T (LDS-staged A; row-exclusive blocks) ----
__global__ __launch_bounds__(256) void k_gemm_inplace(__hip_bfloat16* __restrict__ P,
                                                      const __hip_bfloat16* __restrict__ B){
  __shared__ __hip_bfloat16 sA[64*264];
  int tid = threadIdx.x;
  int mBase = blockIdx.x*64;
  {
    int r = tid >> 2;
    int c0 = (tid & 3)*64;
    int grow = mBase + r; if(grow >= NN) grow = NN-1;
    const __hip_bfloat16* srcp = P + (size_t)grow*256 + c0;
    #pragma unroll
    for(int j=0;j<8;j++) *(bf16x8*)(&sA[r*264 + c0 + j*8]) = LD8(srcp + j*8);
  }
  __syncthreads();
  int w = tid>>6, lane = tid&63, l16 = lane&15, quad = lane>>4, quad8 = quad*8;
  const __hip_bfloat16* arow = &sA[(w*16 + l16)*264 + quad8];
  float4v acc[16];
  #pragma unroll
  for(int nt=0;nt<16;nt++){ acc[nt][0]=0.f; acc[nt][1]=0.f; acc[nt][2]=0.f; acc[nt][3]=0.f; }
  for(int k0=0;k0<256;k0+=32){
    bf16x8 a = *(const bf16x8*)(arow + k0);
    #pragma unroll
    for(int nt=0;nt<16;nt++)
      acc[nt] = MFMA16(a, LD8(B + (size_t)(nt*16+l16)*256 + k0 + quad8), acc[nt]);
  }
  #pragma unroll
  for(int nt=0;nt<16;nt++){
    int col = nt*16 + l16;
    #pragma unroll
    for(int r=0;r<4;r++){
      int row = mBase + w*16 + quad*4 + r;
      if(row < NN) P[(size_t)row*256 + col] = f2bf(acc[nt][r]);
    }
  }
}

// ---------------- fused GAT edge phase: logits+softmax+aggregate+ELU (per node) ------
__global__ __launch_bounds__(256) void k_node_fused(const __hip_bfloat16* __restrict__ Q,
                                                    __hip_bfloat16* __restrict__ P,
                                                    const int* __restrict__ offp,
                                                    const int* __restrict__ csr_src,
                                                    const float* __restrict__ attf,
                                                    const float* __restrict__ gbiasf){
  __shared__ float slog[DEGMAX*4];
  __shared__ int ssrc[DEGMAX];
  int node = blockIdx.x;
  int tid = threadIdx.x;
  int s0 = offp[node], s1 = offp[node+1];
  if(s0 < 0) s0 = 0; if(s0 > NE) s0 = NE;
  if(s1 < s0) s1 = s0; if(s1 > NE) s1 = NE;
  int deg = s1 - s0; if(deg > DEGMAX) deg = DEGMAX;
  if(tid < deg){
    unsigned sv = (unsigned)csr_src[s0 + tid];
    ssrc[tid] = (sv < NN) ? (int)sv : 0;
  }
  __syncthreads();
  int w = tid>>6, lane = tid&63;
  for(int idx=w; idx<deg; idx+=4){
    const __hip_bfloat16* pl = Q + (size_t)ssrc[idx]*256;
    const __hip_bfloat16* pr = P + (size_t)node*256;
    float a[4];
    #pragma unroll
    for(int h=0;h<4;h++){
      float v = bf2f(pl[h*64+lane]) + bf2f(pr[h*64+lane]);
      v = (v > 0.f) ? v : 0.2f*v;
      a[h] = v * attf[h*64+lane];
    }
    #pragma unroll
    for(int h=0;h<4;h++){
      float s = a[h];
      s += __shfl_xor(s, 1, 64);
      s += __shfl_xor(s, 2, 64);
      s += __shfl_xor(s, 4, 64);
      s += __shfl_xor(s, 8, 64);
      s += __shfl_xor(s, 16, 64);
      s += __shfl_xor(s, 32, 64);
      if(lane == 0) slog[idx*4 + h] = s;
    }
  }
  __syncthreads();
  if(tid < 4){
    int h = tid;
    float m = -1e30f;
    for(int i=0;i<deg;i++) m = fmaxf(m, slog[i*4+h]);
    float den = 0.f;
    for(int i=0;i<deg;i++) den += __expf(slog[i*4+h] - m);
    float inv = (den > 0.f) ? 1.f/den : 0.f;
    for(int i=0;i<deg;i++) slog[i*4+h] = __expf(slog[i*4+h] - m)*inv;
  }
  __syncthreads();
  int d = tid, h = d>>6;
  float acc = 0.f;
  for(int i=0;i<deg;i++) acc += slog[i*4+h] * bf2f(Q[(size_t)ssrc[i]*256 + d]);
  acc += gbiasf[d];
  acc = (acc > 0.f) ? acc : (__expf(acc) - 1.f);   // ELU
  P[(size_t)node*256 + d] = f2bf(acc);
}

// ---------------- persistent LSTM: 512 threads (8 waves), 16 rows/block --------------
// Wave w owns cols [w*32,(w+1)*32) for ALL 4 gates -> nt = g*2+tc, acc = 8 tiles
// (32 AGPR). __launch_bounds__(512,4): 128-reg unified budget, 16 waves/CU, 2 blk/CU.
// #pragma unroll 2 on k0 loops: caps in-flight B-fragments (~16 loads) so the
// compiler cannot hoist 64 loads and spill (r7-r12: WRITE 550-757MB scratch traffic).
__global__ __launch_bounds__(512, 4) void k_lstm12(const __hip_bfloat16* __restrict__ ctx,
                                                   const __hip_bfloat16* __restrict__ Wc,
                                                   const __hip_bfloat16* __restrict__ Whh,
                                                   const float* __restrict__ u_vec,
                                                   const float* __restrict__ bc_vec,
                                                   const float* __restrict__ initwf,
                                                   const float* __restrict__ outwf,
                                                   const float* __restrict__ sc,
                                                   float* __restrict__ out){
  __shared__ __hip_bfloat16 sgx[16*SGXP];    // 32.9KB: GX+bc, [row][gatecol]
  __shared__ __hip_bfloat16 sh[16*264];      // h tile (bank-padded)
  __shared__ float spart[512];               // init-reduction scratch
  __shared__ float spartw[128];              // per-wave out-projection partials
  __shared__ float sprev[16];
  int tid = threadIdx.x;
  int mBase = blockIdx.x*16;                 // 1250*16 == NN exactly
  int w = tid>>6, lane = tid&63, l16 = lane&15, quad = lane>>4, quad8 = quad*8;
  // h0 = ctx rows (512 threads: 16 rows x 32 chunks of 8)
  {
    int r = tid >> 5, c0 = (tid & 31)*8;
    *(bf16x8*)(&sh[r*264 + c0]) = LD8(ctx + (size_t)(mBase + r)*256 + c0);
  }
  __syncthreads();
  // prev0 = ctx @ init_w + init_b
  {
    int r = tid >> 5, c0 = (tid & 31)*8;
    float part = 0.f;
    #pragma unroll
    for(int j=0;j<8;j++) part += bf2f(sh[r*264 + c0 + j]) * initwf[c0 + j];
    spart[tid] = part;
  }
  __syncthreads();
  if(tid < 16){
    float s = 0.f;
    #pragma unroll
    for(int j=0;j<32;j++) s += spart[tid*32 + j];
    sprev[tid] = s + sc[0];
  }
  // per-thread constants: this wave's 32-col slab, 4 gates
  float ureg[8], owreg[2];
  #pragma unroll
  for(int g=0;g<4;g++)
    #pragma unroll
    for(int tc=0;tc<2;tc++) ureg[g*2+tc] = u_vec[g*256 + w*32 + tc*16 + l16];
  #pragma unroll
  for(int tc=0;tc<2;tc++) owreg[tc] = outwf[w*32 + tc*16 + l16];
  float outb = sc[1];
  // GX phase: acc = ctx@Wc^T (4 gates x 32 cols), +bc -> sgx
  {
    float4v acc[8];
    #pragma unroll
    for(int nt=0;nt<8;nt++){ acc[nt][0]=0.f; acc[nt][1]=0.f; acc[nt][2]=0.f; acc[nt][3]=0.f; }
    #pragma unroll 2
    for(int k0=0;k0<256;k0+=32){
      bf16x8 a = *(const bf16x8*)(&sh[l16*264 + k0 + quad8]);
      #pragma unroll
      for(int nt=0;nt<8;nt++){
        int brow = (nt>>1)*256 + w*32 + (nt&1)*16 + l16;
        acc[nt] = MFMA16(a, LD8(Wc + (size_t)brow*256 + k0 + quad8), acc[nt]);
      }
    }
    #pragma unroll
    for(int nt=0;nt<8;nt++){
      int gc = (nt>>1)*256 + w*32 + (nt&1)*16 + l16;
      float bcv = bc_vec[gc];
      #pragma unroll
      for(int r=0;r<4;r++)
        sgx[(quad*4 + r)*SGXP + gc] = f2bf(acc[nt][r] + bcv);
    }
  }
  __syncthreads();   // sgx + sprev visible
  float creg[8];
  #pragma unroll
  for(int i=0;i<8;i++) creg[i] = 0.f;
  for(int step=0; step<TOUT; step++){
    // (a) gates GEMM: acc[g*2+tc] = h @ Whh^T slab
    float4v acc[8];
    #pragma unroll
    for(int nt=0;nt<8;nt++){ acc[nt][0]=0.f; acc[nt][1]=0.f; acc[nt][2]=0.f; acc[nt][3]=0.f; }
    #pragma unroll 2
    for(int k0=0;k0<256;k0+=32){
      bf16x8 a = *(const bf16x8*)(&sh[l16*264 + k0 + quad8]);
      #pragma unroll
      for(int nt=0;nt<8;nt++){
        int brow = (nt>>1)*256 + w*32 + (nt&1)*16 + l16;
        acc[nt] = MFMA16(a, LD8(Whh + (size_t)brow*256 + k0 + quad8), acc[nt]);
      }
    }
    __syncthreads();   // S1: all sh reads done; sprev (from prev step) visible
    // (b) in-register activation + h write + out-projection partials
    float hsum[4] = {0.f, 0.f, 0.f, 0.f};
    #pragma unroll
    for(int tc=0;tc<2;tc++){
      int col = w*32 + tc*16 + l16;
      #pragma unroll
      for(int r=0;r<4;r++){
        int row = quad*4 + r;
        float p = sprev[row];
        float g0 = acc[tc][r]     + bf2f(sgx[row*SGXP + col])       + p*ureg[tc];
        float g1 = acc[2+tc][r]   + bf2f(sgx[row*SGXP + 256 + col]) + p*ureg[2+tc];
        float g2 = acc[4+tc][r]   + bf2f(sgx[row*SGXP + 512 + col]) + p*ureg[4+tc];
        float g3 = acc[6+tc][r]   + bf2f(sgx[row*SGXP + 768 + col]) + p*ureg[6+tc];
        float iv = sigmoidf_(g0), fv = sigmoidf_(g1);
        float gv = tanhf_(g2),    ov = sigmoidf_(g3);
        float cn = fv*creg[tc*4+r] + iv*gv;
        creg[tc*4+r] = cn;
        float hn = ov * tanhf_(cn);
        sh[row*264 + col] = f2bf(hn);
        hsum[r] += hn * owreg[tc];
      }
    }
    #pragma unroll
    for(int r=0;r<4;r++){
      hsum[r] += __shfl_xor(hsum[r], 1, 64);
      hsum[r] += __shfl_xor(hsum[r], 2, 64);
      hsum[r] += __shfl_xor(hsum[r], 4, 64);
      hsum[r] += __shfl_xor(hsum[r], 8, 64);
    }
    if(l16 == 0){
      #pragma unroll
      for(int r=0;r<4;r++) spartw[w*16 + quad*4 + r] = hsum[r];
    }
    __syncthreads();   // S2: sh writes + spartw visible
    if(tid < 16){
      float s = outb;
      #pragma unroll
      for(int ww=0;ww<8;ww++) s += spartw[ww*16 + tid];
      sprev[tid] = s;
      out[(size_t)(mBase + tid)*TOUT + step] = s;
    }
    // next S1 makes sprev visible before next activation
  }
}

// ---------------- launch ----------------
extern "C" void kernel_launch(void* const* d_in, const int* in_sizes, int n_in,
                              void* d_out, int out_size, void* d_ws, size_t ws_size,
                              hipStream_t stream){
  const void* x      = d_in[0];
  const int*  ei     = (const int*)d_in[1];
  const void* w_src  = d_in[2];
  const void* w_dst  = d_in[3];
  const void* att    = d_in[4];
  const void* gbias  = d_in[5];
  const void* mlp_w  = d_in[6];
  const void* mlp_b  = d_in[7];
  const void* w_ih   = d_in[8];
  const void* w_hh   = d_in[9];
  const void* b_ih   = d_in[10];
  const void* b_hh   = d_in[11];
  const void* init_w = d_in[12];
  const void* init_b = d_in[13];
  const void* out_w  = d_in[14];
  const void* out_b  = d_in[15];
  float* out = (float*)d_out;
  const int* srcp = ei;
  const int* dstp = ei + NE;
  (void)in_sizes; (void)n_in;

  char* ws = (char*)d_ws;
  size_t off = 0;
  auto alloc = [&](size_t bytes)->void*{
    void* p = ws + off;
    off += (bytes + 255) & ~(size_t)255;
    return p;
  };
  __hip_bfloat16* P = (__hip_bfloat16*)alloc((size_t)NN*256*2);  // x -> xr -> layer out -> ctx
  __hip_bfloat16* Q = (__hip_bfloat16*)alloc((size_t)NN*256*2);  // xl per layer
  int* deg      = (int*)alloc((size_t)NN*4);
  int* offp     = (int*)alloc((size_t)(NN+1)*4);
  int* cursor   = (int*)alloc((size_t)NN*4);
  int* csr_src  = (int*)alloc((size_t)NE*4);
  __hip_bfloat16* wsrcT = (__hip_bfloat16*)alloc((size_t)131072*2);
  __hip_bfloat16* wdstT = (__hip_bfloat16*)alloc((size_t)131072*2);
  __hip_bfloat16* whhb  = (__hip_bfloat16*)alloc((size_t)262144*2);
  __hip_bfloat16* Wc    = (__hip_bfloat16*)alloc((size_t)262144*2);
  float* u_vec  = (float*)alloc(1024*4);
  float* bc_vec = (float*)alloc(1024*4);
  float* attf   = (float*)alloc(512*4);
  float* gbiasf = (float*)alloc(512*4);
  float* initwf = (float*)alloc(256*4);
  float* outwf  = (float*)alloc(256*4);
  float* sc     = (float*)alloc(2*4);
  int*   flag   = (int*)alloc(4);
  // total ~23.6 MB

  if(off > ws_size){
    k_fail<<<(out_size + 255)/256, 256, 0, stream>>>(out, out_size);
    return;
  }

  // dtype detect + CSR + prep
  k_detect<<<1, 256, 0, stream>>>(x, flag);
  hipMemsetAsync(deg, 0, (size_t)NN*4, stream);
  hipMemsetAsync(csr_src, 0xFF, (size_t)NE*4, stream);
  k_count<<<NE/256, 256, 0, stream>>>(dstp, deg);
  k_scan<<<1, 256, 0, stream>>>(deg, offp, cursor);
  k_fill<<<NE/256, 256, 0, stream>>>(srcp, dstp, cursor, csr_src);
  k_cvt_x<<<NN, 256, 0, stream>>>(x, flag, P);
  k_prep<<<1024, 256, 0, stream>>>(w_src, w_dst, w_hh, flag, wsrcT, wdstT, whhb);
  k_prep_wc<<<1024, 256, 0, stream>>>(w_ih, mlp_w, flag, Wc);
  k_prep_small<<<4, 256, 0, stream>>>(w_ih, mlp_w, mlp_b, b_ih, b_hh, att, gbias,
                                      init_w, init_b, out_w, out_b, flag,
                                      u_vec, bc_vec, attf, gbiasf, initwf, outwf, sc);

  // GAT layers: Q = P@Wsrc^T (xl); P = P@Wdst^T in-place (xr); fused edge phase -> P
  dim3 g64(313, 4);
  for(int l=0;l<2;l++){
    k_gemm_nt_bf<<<g64, 256, 0, stream>>>(P, wsrcT + l*65536, Q);
    k_gemm_inplace<<<313, 256, 0, stream>>>(P, wdstT + l*65536);
    k_node_fused<<<NN, 256, 0, stream>>>(Q, P, offp, csr_src, attf + l*256, gbiasf + l*256);
  }

  // persistent LSTM decoder: bounded unroll, no spills
  k_lstm12<<<1250, 512, 0, stream>>>(P, Wc, whhb, u_vec, bc_vec, initwf, outwf, sc, out);
}

// Round 14
// 1426.327 us; speedup vs baseline: 1.8253x; 1.2247x over previous
//
#include <hip/hip_runtime.h>
#include <hip/hip_bf16.h>

#define NN 20000
#define NE 320000
#define TOUT 12
#define DEGMAX 96
#define SGXP 1028   // sgx row stride (bf16): quads hit disjoint bank groups

typedef __bf16 bf16x8 __attribute__((ext_vector_type(8)));
typedef float float4v __attribute__((ext_vector_type(4)));

#define LD8(p) (*(const bf16x8*)(p))
#define MFMA16(a,b,c) __builtin_amdgcn_mfma_f32_16x16x32_bf16((a),(b),(c),0,0,0)

__device__ __forceinline__ float bf2f(const __hip_bfloat16 v){ return __bfloat162float(v); }
__device__ __forceinline__ __hip_bfloat16 f2bf(float v){ return __float2bfloat16(v); }
__device__ __forceinline__ float sigmoidf_(float x){ return 1.0f/(1.0f + __expf(-x)); }
__device__ __forceinline__ float tanhf_(float x){ float e = __expf(2.f*x); return 1.f - 2.f/(e + 1.f); }
__device__ __forceinline__ float rdf(const void* p, int i, int f32){
  return f32 ? ((const float*)p)[i] : __bfloat162float(((const __hip_bfloat16*)p)[i]);
}

// ---------------- input dtype detector ----------------
__global__ void k_detect(const void* xraw, int* flag){
  __shared__ int cnt;
  if(threadIdx.x == 0) cnt = 0;
  __syncthreads();
  const unsigned* w = (const unsigned*)xraw;
  int local = 0;
  for(int i = threadIdx.x; i < 4096; i += 256){
    unsigned b = (w[i] >> 8) & 0x7F;
    if(b >= 0x33 && b <= 0x3F) local++;
  }
  atomicAdd(&cnt, local);
  __syncthreads();
  if(threadIdx.x == 0) *flag = (cnt > 2048) ? 0 : 1;   // 1 => fp32 inputs
}

// guard signature: constant 256.0 everywhere (fp32 out)
__global__ void k_fail(float* out, int n){
  int i = blockIdx.x*256 + threadIdx.x;
  if(i < n) out[i] = 256.0f;
}

// ---------------- CSR build ----------------
__global__ void k_count(const int* __restrict__ dst, int* __restrict__ deg){
  int e = blockIdx.x*256 + threadIdx.x;
  if(e < NE){
    unsigned d = (unsigned)dst[e];
    if(d < NN) atomicAdd(&deg[d], 1);
  }
}

__global__ void k_scan(const int* __restrict__ deg, int* __restrict__ offp, int* __restrict__ cursor){
  __shared__ int part[256];
  __shared__ int excl[257];
  const int CH = (NN + 255)/256;
  int tid = threadIdx.x;
  int lo = tid*CH;
  int hi = lo + CH; if(hi > NN) hi = NN;
  int s = 0;
  for(int i=lo;i<hi;i++) s += deg[i];
  part[tid] = s;
  __syncthreads();
  if(tid == 0){
    int run = 0;
    for(int i=0;i<256;i++){ excl[i] = run; run += part[i]; }
    excl[256] = run;
  }
  __syncthreads();
  int run = excl[tid];
  for(int i=lo;i<hi;i++){ offp[i] = run; cursor[i] = run; run += deg[i]; }
  if(tid == 0) offp[NN] = excl[256];
}

__global__ void k_fill(const int* __restrict__ src, const int* __restrict__ dst,
                       int* __restrict__ cursor, int* __restrict__ csr_src){
  int e = blockIdx.x*256 + threadIdx.x;
  if(e >= NE) return;
  unsigned d = (unsigned)dst[e];
  if(d >= NN) return;
  unsigned p = (unsigned)atomicAdd(&cursor[d], 1);
  if(p < NE){
    unsigned sv = (unsigned)src[e];
    csr_src[p] = (sv < NN) ? (int)sv : 0;
  }
}

// ---------------- conversions / weight prep ----------------
__global__ void k_cvt_x(const void* __restrict__ x, const int* __restrict__ flag,
                        __hip_bfloat16* __restrict__ xb){
  int i = blockIdx.x*256 + threadIdx.x;
  int f = *flag;
  if(i < NN*256) xb[i] = f2bf(rdf(x, i, f));
}

__global__ void k_prep(const void* __restrict__ w_src, const void* __restrict__ w_dst,
                       const void* __restrict__ w_hh, const int* __restrict__ flag,
                       __hip_bfloat16* __restrict__ wsrcT, __hip_bfloat16* __restrict__ wdstT,
                       __hip_bfloat16* __restrict__ whhb){
  int tid = blockIdx.x*256 + threadIdx.x;
  int f = *flag;
  if(tid < 131072){
    int l = tid >> 16, r = tid & 65535, o = r >> 8, i = r & 255;
    wsrcT[tid] = f2bf(rdf(w_src, l*65536 + i*256 + o, f));
    wdstT[tid] = f2bf(rdf(w_dst, l*65536 + i*256 + o, f));
  }
  if(tid < 262144) whhb[tid] = f2bf(rdf(w_hh, tid, f));
}

// Wc[g,k] = sum_j Wih[g,j] * mlp_w[j, 1+k]
__global__ void k_prep_wc(const void* __restrict__ wih, const void* __restrict__ mlp_w,
                          const int* __restrict__ flag, __hip_bfloat16* __restrict__ Wc){
  int g = blockIdx.x;
  int k = threadIdx.x;
  int f = *flag;
  float s = 0.f;
  for(int j=0;j<256;j++) s += rdf(wih, g*256+j, f) * rdf(mlp_w, j*257 + 1 + k, f);
  Wc[g*256+k] = f2bf(s);
}

__global__ void k_prep_small(const void* __restrict__ wih, const void* __restrict__ mlp_w,
                             const void* __restrict__ mlp_b,
                             const void* __restrict__ b_ih, const void* __restrict__ b_hh,
                             const void* __restrict__ att, const void* __restrict__ gbias,
                             const void* __restrict__ init_w, const void* __restrict__ init_b,
                             const void* __restrict__ out_w, const void* __restrict__ out_b,
                             const int* __restrict__ flag,
                             float* __restrict__ u, float* __restrict__ bc,
                             float* __restrict__ attf, float* __restrict__ gbiasf,
                             float* __restrict__ initwf, float* __restrict__ outwf,
                             float* __restrict__ sc){
  int g = blockIdx.x*256 + threadIdx.x;
  int f = *flag;
  if(g < 1024){
    float su = 0.f, sb = 0.f;
    for(int j=0;j<256;j++){
      float w = rdf(wih, g*256+j, f);
      su += w * rdf(mlp_w, j*257, f);
      sb += w * rdf(mlp_b, j, f);
    }
    u[g] = su;
    bc[g] = sb + rdf(b_ih, g, f) + rdf(b_hh, g, f);
  }
  if(g < 512){ attf[g] = rdf(att, g, f); gbiasf[g] = rdf(gbias, g, f); }
  if(g < 256){ initwf[g] = rdf(init_w, g, f); outwf[g] = rdf(out_w, g, f); }
  if(g == 0){ sc[0] = rdf(init_b, 0, f); sc[1] = rdf(out_b, 0, f); }
}

// ---------------- NT GEMM (out-of-place): Q[m,n] = sum_k P[m,k]*B[n,k] ----------------
__global__ __launch_bounds__(256) void k_gemm_nt_bf(const __hip_bfloat16* __restrict__ A,
                                                    const __hip_bfloat16* __restrict__ B,
                                                    __hip_bfloat16* __restrict__ Cb){
  int wave = threadIdx.x >> 6;
  int lane = threadIdx.x & 63;
  int l16 = lane & 15, quad = lane >> 4, quad8 = quad*8;
  int mBase = blockIdx.x*64 + wave*16;
  int nBase = blockIdx.y*64;
  int arow = mBase + l16; if(arow >= NN) arow = NN-1;
  const __hip_bfloat16* aptr = A + (size_t)arow*256 + quad8;
  float4v acc[4];
  #pragma unroll
  for(int nt=0;nt<4;nt++){ acc[nt][0]=0.f; acc[nt][1]=0.f; acc[nt][2]=0.f; acc[nt][3]=0.f; }
  for(int k0=0;k0<256;k0+=32){
    bf16x8 a = LD8(aptr + k0);
    #pragma unroll
    for(int nt=0;nt<4;nt++){
      const __hip_bfloat16* bptr = B + (size_t)(nBase + nt*16 + l16)*256 + k0 + quad8;
      acc[nt] = MFMA16(a, LD8(bptr), acc[nt]);
    }
  }
  #pragma unroll
  for(int nt=0;nt<4;nt++){
    int col = nBase + nt*16 + l16;
    #pragma unroll
    for(int r=0;r<4;r++){
      int row = mBase + quad*4 + r;
      if(row < NN) Cb[(size_t)row*256 + col] = f2bf(acc[nt][r]);
    }
  }
}

// ---------------- in-place NT GEMM: P = P@B^T (LDS-staged A; row-exclusive blocks) ----
__global__ __launch_bounds__(256) void k_gemm_inplace(__hip_bfloat16* __restrict__ P,
                                                      const __hip_bfloat16* __restrict__ B){
  __shared__ __hip_bfloat16 sA[64*264];
  int tid = threadIdx.x;
  int mBase = blockIdx.x*64;
  {
    int r = tid >> 2;
    int c0 = (tid & 3)*64;
    int grow = mBase + r; if(grow >= NN) grow = NN-1;
    const __hip_bfloat16* srcp = P + (size_t)grow*256 + c0;
    #pragma unroll
    for(int j=0;j<8;j++) *(bf16x8*)(&sA[r*264 + c0 + j*8]) = LD8(srcp + j*8);
  }
  __syncthreads();
  int w = tid>>6, lane = tid&63, l16 = lane&15, quad = lane>>4, quad8 = quad*8;
  const __hip_bfloat16* arow = &sA[(w*16 + l16)*264 + quad8];
  float4v acc[16];
  #pragma unroll
  for(int nt=0;nt<16;nt++){ acc[nt][0]=0.f; acc[nt][1]=0.f; acc[nt][2]=0.f; acc[nt][3]=0.f; }
  for(int k0=0;k0<256;k0+=32){
    bf16x8 a = *(const bf16x8*)(arow + k0);
    #pragma unroll
    for(int nt=0;nt<16;nt++)
      acc[nt] = MFMA16(a, LD8(B + (size_t)(nt*16+l16)*256 + k0 + quad8), acc[nt]);
  }
  #pragma unroll
  for(int nt=0;nt<16;nt++){
    int col = nt*16 + l16;
    #pragma unroll
    for(int r=0;r<4;r++){
      int row = mBase + w*16 + quad*4 + r;
      if(row < NN) P[(size_t)row*256 + col] = f2bf(acc[nt][r]);
    }
  }
}

// ---------------- fused GAT edge phase: logits+softmax+aggregate+ELU (per node) ------
__global__ __launch_bounds__(256) void k_node_fused(const __hip_bfloat16* __restrict__ Q,
                                                    __hip_bfloat16* __restrict__ P,
                                                    const int* __restrict__ offp,
                                                    const int* __restrict__ csr_src,
                                                    const float* __restrict__ attf,
                                                    const float* __restrict__ gbiasf){
  __shared__ float slog[DEGMAX*4];
  __shared__ int ssrc[DEGMAX];
  int node = blockIdx.x;
  int tid = threadIdx.x;
  int s0 = offp[node], s1 = offp[node+1];
  if(s0 < 0) s0 = 0; if(s0 > NE) s0 = NE;
  if(s1 < s0) s1 = s0; if(s1 > NE) s1 = NE;
  int deg = s1 - s0; if(deg > DEGMAX) deg = DEGMAX;
  if(tid < deg){
    unsigned sv = (unsigned)csr_src[s0 + tid];
    ssrc[tid] = (sv < NN) ? (int)sv : 0;
  }
  __syncthreads();
  int w = tid>>6, lane = tid&63;
  for(int idx=w; idx<deg; idx+=4){
    const __hip_bfloat16* pl = Q + (size_t)ssrc[idx]*256;
    const __hip_bfloat16* pr = P + (size_t)node*256;
    float a[4];
    #pragma unroll
    for(int h=0;h<4;h++){
      float v = bf2f(pl[h*64+lane]) + bf2f(pr[h*64+lane]);
      v = (v > 0.f) ? v : 0.2f*v;
      a[h] = v * attf[h*64+lane];
    }
    #pragma unroll
    for(int h=0;h<4;h++){
      float s = a[h];
      s += __shfl_xor(s, 1, 64);
      s += __shfl_xor(s, 2, 64);
      s += __shfl_xor(s, 4, 64);
      s += __shfl_xor(s, 8, 64);
      s += __shfl_xor(s, 16, 64);
      s += __shfl_xor(s, 32, 64);
      if(lane == 0) slog[idx*4 + h] = s;
    }
  }
  __syncthreads();
  if(tid < 4){
    int h = tid;
    float m = -1e30f;
    for(int i=0;i<deg;i++) m = fmaxf(m, slog[i*4+h]);
    float den = 0.f;
    for(int i=0;i<deg;i++) den += __expf(slog[i*4+h] - m);
    float inv = (den > 0.f) ? 1.f/den : 0.f;
    for(int i=0;i<deg;i++) slog[i*4+h] = __expf(slog[i*4+h] - m)*inv;
  }
  __syncthreads();
  int d = tid, h = d>>6;
  float acc = 0.f;
  for(int i=0;i<deg;i++) acc += slog[i*4+h] * bf2f(Q[(size_t)ssrc[i]*256 + d]);
  acc += gbiasf[d];
  acc = (acc > 0.f) ? acc : (__expf(acc) - 1.f);   // ELU
  P[(size_t)node*256 + d] = f2bf(acc);
}

// ---------------- persistent LSTM: 512 threads (8 waves), 32 rows/block --------------
// r13 was L2-BW bound: 1250 blk x 12 steps x 512KB Whh = 7.9GB L2 reads at ~6.8TB/s
// effective. This version: M=32 (625 blocks, 2 row-tiles/wave -> each B-fragment used
// twice -> traffic halved to 3.9GB) + per-block k-phase rotation (de-syncs address
// streams across blocks -> less L2 bank camping). acc = 16 tiles (64 AGPR) is safe
// under (512,2)'s 256-reg budget (1 block/CU by LDS anyway); unroll 2 caps hoisting.
__global__ __launch_bounds__(512, 2) void k_lstm12(const __hip_bfloat16* __restrict__ ctx,
                                                   const __hip_bfloat16* __restrict__ Wc,
                                                   const __hip_bfloat16* __restrict__ Whh,
                                                   const float* __restrict__ u_vec,
                                                   const float* __restrict__ bc_vec,
                                                   const float* __restrict__ initwf,
                                                   const float* __restrict__ outwf,
                                                   const float* __restrict__ sc,
                                                   float* __restrict__ out){
  __shared__ __hip_bfloat16 sgx[32*SGXP];    // 65.8KB: GX+bc, [row][gatecol]
  __shared__ __hip_bfloat16 sh[32*264];      // 16.9KB h tile (bank-padded)
  __shared__ float spart[512];               // init-reduction scratch
  __shared__ float spartw[32*8];             // per-wave out-projection partials
  __shared__ float sprev[32];
  int tid = threadIdx.x;
  int mBase = blockIdx.x*32;                 // 625*32 == NN exactly
  int cs = tid>>6, lane = tid&63, l16 = lane&15, quad = lane>>4, quad8 = quad*8;
  int phase = blockIdx.x & 7;
  // h0 = ctx rows (512 threads: 32 rows x 16 chunks of 16)
  {
    int r = tid >> 4, c0 = (tid & 15)*16;
    const __hip_bfloat16* srcp = ctx + (size_t)(mBase + r)*256 + c0;
    *(bf16x8*)(&sh[r*264 + c0])     = LD8(srcp);
    *(bf16x8*)(&sh[r*264 + c0 + 8]) = LD8(srcp + 8);
  }
  __syncthreads();
  // prev0 = ctx @ init_w + init_b
  {
    int r = tid >> 4, c0 = (tid & 15)*16;
    float part = 0.f;
    #pragma unroll
    for(int j=0;j<16;j++) part += bf2f(sh[r*264 + c0 + j]) * initwf[c0 + j];
    spart[tid] = part;
  }
  __syncthreads();
  if(tid < 32){
    float s = 0.f;
    #pragma unroll
    for(int j=0;j<16;j++) s += spart[tid*16 + j];
    sprev[tid] = s + sc[0];
  }
  // per-thread constants: this wave's 32-col slab, 4 gates
  float ureg[8], owreg[2];
  #pragma unroll
  for(int g=0;g<4;g++)
    #pragma unroll
    for(int tc=0;tc<2;tc++) ureg[g*2+tc] = u_vec[g*256 + cs*32 + tc*16 + l16];
  #pragma unroll
  for(int tc=0;tc<2;tc++) owreg[tc] = outwf[cs*32 + tc*16 + l16];
  float outb = sc[1];
  // GX phase: acc = ctx@Wc^T (4 gates x 32 cols x 2 row-tiles), +bc -> sgx
  {
    float4v acc[16];
    #pragma unroll
    for(int nt=0;nt<16;nt++){ acc[nt][0]=0.f; acc[nt][1]=0.f; acc[nt][2]=0.f; acc[nt][3]=0.f; }
    #pragma unroll 2
    for(int ki=0;ki<8;ki++){
      int k0 = ((ki + phase) & 7)*32;
      bf16x8 a0 = *(const bf16x8*)(&sh[l16*264 + k0 + quad8]);
      bf16x8 a1 = *(const bf16x8*)(&sh[(16 + l16)*264 + k0 + quad8]);
      #pragma unroll
      for(int nt=0;nt<8;nt++){
        int brow = (nt>>1)*256 + cs*32 + (nt&1)*16 + l16;
        bf16x8 b = LD8(Wc + (size_t)brow*256 + k0 + quad8);
        acc[nt]   = MFMA16(a0, b, acc[nt]);
        acc[8+nt] = MFMA16(a1, b, acc[8+nt]);
      }
    }
    #pragma unroll
    for(int rt=0;rt<2;rt++)
      #pragma unroll
      for(int nt=0;nt<8;nt++){
        int gc = (nt>>1)*256 + cs*32 + (nt&1)*16 + l16;
        float bcv = bc_vec[gc];
        #pragma unroll
        for(int r=0;r<4;r++)
          sgx[(rt*16 + quad*4 + r)*SGXP + gc] = f2bf(acc[rt*8+nt][r] + bcv);
      }
  }
  __syncthreads();   // sgx + sprev visible
  float creg[16];    // idx rt*8 + tc*4 + r
  #pragma unroll
  for(int i=0;i<16;i++) creg[i] = 0.f;
  for(int step=0; step<TOUT; step++){
    // (a) gates GEMM: acc[rt*8 + g*2 + tc] = h @ Whh^T slab; B reused across rt
    float4v acc[16];
    #pragma unroll
    for(int nt=0;nt<16;nt++){ acc[nt][0]=0.f; acc[nt][1]=0.f; acc[nt][2]=0.f; acc[nt][3]=0.f; }
    #pragma unroll 2
    for(int ki=0;ki<8;ki++){
      int k0 = ((ki + phase) & 7)*32;
      bf16x8 a0 = *(const bf16x8*)(&sh[l16*264 + k0 + quad8]);
      bf16x8 a1 = *(const bf16x8*)(&sh[(16 + l16)*264 + k0 + quad8]);
      #pragma unroll
      for(int nt=0;nt<8;nt++){
        int brow = (nt>>1)*256 + cs*32 + (nt&1)*16 + l16;
        bf16x8 b = LD8(Whh + (size_t)brow*256 + k0 + quad8);
        acc[nt]   = MFMA16(a0, b, acc[nt]);
        acc[8+nt] = MFMA16(a1, b, acc[8+nt]);
      }
    }
    __syncthreads();   // S1: all sh reads done; sprev (from prev step) visible
    // (b) in-register activation + h write + out-projection partials
    float hsum[8] = {0.f,0.f,0.f,0.f,0.f,0.f,0.f,0.f};   // rt*4 + r
    #pragma unroll
    for(int rt=0;rt<2;rt++)
      #pragma unroll
      for(int tc=0;tc<2;tc++){
        int col = cs*32 + tc*16 + l16;
        #pragma unroll
        for(int r=0;r<4;r++){
          int row = rt*16 + quad*4 + r;
          float p = sprev[row];
          float g0 = acc[rt*8 + tc][r]     + bf2f(sgx[row*SGXP + col])       + p*ureg[tc];
          float g1 = acc[rt*8 + 2 + tc][r] + bf2f(sgx[row*SGXP + 256 + col]) + p*ureg[2+tc];
          float g2 = acc[rt*8 + 4 + tc][r] + bf2f(sgx[row*SGXP + 512 + col]) + p*ureg[4+tc];
          float g3 = acc[rt*8 + 6 + tc][r] + bf2f(sgx[row*SGXP + 768 + col]) + p*ureg[6+tc];
          float iv = sigmoidf_(g0), fv = sigmoidf_(g1);
          float gv = tanhf_(g2),    ov = sigmoidf_(g3);
          float cn = fv*creg[rt*8 + tc*4 + r] + iv*gv;
          creg[rt*8 + tc*4 + r] = cn;
          float hn = ov * tanhf_(cn);
          sh[row*264 + col] = f2bf(hn);
          hsum[rt*4 + r] += hn * owreg[tc];
        }
      }
    #pragma unroll
    for(int rr=0;rr<8;rr++){
      hsum[rr] += __shfl_xor(hsum[rr], 1, 64);
      hsum[rr] += __shfl_xor(hsum[rr], 2, 64);
      hsum[rr] += __shfl_xor(hsum[rr], 4, 64);
      hsum[rr] += __shfl_xor(hsum[rr], 8, 64);
    }
    if(l16 == 0){
      #pragma unroll
      for(int rt=0;rt<2;rt++)
        #pragma unroll
        for(int r=0;r<4;r++)
          spartw[(rt*16 + quad*4 + r)*8 + cs] = hsum[rt*4 + r];
    }
    __syncthreads();   // S2: sh writes + spartw visible
    if(tid < 32){
      float s = outb;
      #pragma unroll
      for(int c=0;c<8;c++) s += spartw[tid*8 + c];
      sprev[tid] = s;
      out[(size_t)(mBase + tid)*TOUT + step] = s;
    }
    // next S1 makes sprev visible before next activation
  }
}

// ---------------- launch ----------------
extern "C" void kernel_launch(void* const* d_in, const int* in_sizes, int n_in,
                              void* d_out, int out_size, void* d_ws, size_t ws_size,
                              hipStream_t stream){
  const void* x      = d_in[0];
  const int*  ei     = (const int*)d_in[1];
  const void* w_src  = d_in[2];
  const void* w_dst  = d_in[3];
  const void* att    = d_in[4];
  const void* gbias  = d_in[5];
  const void* mlp_w  = d_in[6];
  const void* mlp_b  = d_in[7];
  const void* w_ih   = d_in[8];
  const void* w_hh   = d_in[9];
  const void* b_ih   = d_in[10];
  const void* b_hh   = d_in[11];
  const void* init_w = d_in[12];
  const void* init_b = d_in[13];
  const void* out_w  = d_in[14];
  const void* out_b  = d_in[15];
  float* out = (float*)d_out;
  const int* srcp = ei;
  const int* dstp = ei + NE;
  (void)in_sizes; (void)n_in;

  char* ws = (char*)d_ws;
  size_t off = 0;
  auto alloc = [&](size_t bytes)->void*{
    void* p = ws + off;
    off += (bytes + 255) & ~(size_t)255;
    return p;
  };
  __hip_bfloat16* P = (__hip_bfloat16*)alloc((size_t)NN*256*2);  // x -> xr -> layer out -> ctx
  __hip_bfloat16* Q = (__hip_bfloat16*)alloc((size_t)NN*256*2);  // xl per layer
  int* deg      = (int*)alloc((size_t)NN*4);
  int* offp     = (int*)alloc((size_t)(NN+1)*4);
  int* cursor   = (int*)alloc((size_t)NN*4);
  int* csr_src  = (int*)alloc((size_t)NE*4);
  __hip_bfloat16* wsrcT = (__hip_bfloat16*)alloc((size_t)131072*2);
  __hip_bfloat16* wdstT = (__hip_bfloat16*)alloc((size_t)131072*2);
  __hip_bfloat16* whhb  = (__hip_bfloat16*)alloc((size_t)262144*2);
  __hip_bfloat16* Wc    = (__hip_bfloat16*)alloc((size_t)262144*2);
  float* u_vec  = (float*)alloc(1024*4);
  float* bc_vec = (float*)alloc(1024*4);
  float* attf   = (float*)alloc(512*4);
  float* gbiasf = (float*)alloc(512*4);
  float* initwf = (float*)alloc(256*4);
  float* outwf  = (float*)alloc(256*4);
  float* sc     = (float*)alloc(2*4);
  int*   flag   = (int*)alloc(4);
  // total ~23.6 MB

  if(off > ws_size){
    k_fail<<<(out_size + 255)/256, 256, 0, stream>>>(out, out_size);
    return;
  }

  // dtype detect + CSR + prep
  k_detect<<<1, 256, 0, stream>>>(x, flag);
  hipMemsetAsync(deg, 0, (size_t)NN*4, stream);
  hipMemsetAsync(csr_src, 0xFF, (size_t)NE*4, stream);
  k_count<<<NE/256, 256, 0, stream>>>(dstp, deg);
  k_scan<<<1, 256, 0, stream>>>(deg, offp, cursor);
  k_fill<<<NE/256, 256, 0, stream>>>(srcp, dstp, cursor, csr_src);
  k_cvt_x<<<NN, 256, 0, stream>>>(x, flag, P);
  k_prep<<<1024, 256, 0, stream>>>(w_src, w_dst, w_hh, flag, wsrcT, wdstT, whhb);
  k_prep_wc<<<1024, 256, 0, stream>>>(w_ih, mlp_w, flag, Wc);
  k_prep_small<<<4, 256, 0, stream>>>(w_ih, mlp_w, mlp_b, b_ih, b_hh, att, gbias,
                                      init_w, init_b, out_w, out_b, flag,
                                      u_vec, bc_vec, attf, gbiasf, initwf, outwf, sc);

  // GAT layers: Q = P@Wsrc^T (xl); P = P@Wdst^T in-place (xr); fused edge phase -> P
  dim3 g64(313, 4);
  for(int l=0;l<2;l++){
    k_gemm_nt_bf<<<g64, 256, 0, stream>>>(P, wsrcT + l*65536, Q);
    k_gemm_inplace<<<313, 256, 0, stream>>>(P, wdstT + l*65536);
    k_node_fused<<<NN, 256, 0, stream>>>(Q, P, offp, csr_src, attf + l*256, gbiasf + l*256);
  }

  // persistent LSTM decoder: M=32, halved Whh L2 traffic, k-phase rotation
  k_lstm12<<<625, 512, 0, stream>>>(P, Wc, whhb, u_vec, bc_vec, initwf, outwf, sc, out);
}

// Round 15
// 1248.142 us; speedup vs baseline: 2.0859x; 1.1428x over previous
//
#include <hip/hip_runtime.h>
#include <hip/hip_bf16.h>

#define NN 20000
#define NE 320000
#define TOUT 12
#define DEGMAX 96
#define SGXP 1028   // sgx row stride (bf16): quads hit disjoint bank groups
#define MR 48       // rows per LSTM block (3 row-tiles of 16)
#define NBLK 417    // ceil(20000/48)

typedef __bf16 bf16x8 __attribute__((ext_vector_type(8)));
typedef float float4v __attribute__((ext_vector_type(4)));

#define LD8(p) (*(const bf16x8*)(p))
#define MFMA16(a,b,c) __builtin_amdgcn_mfma_f32_16x16x32_bf16((a),(b),(c),0,0,0)

__device__ __forceinline__ float bf2f(const __hip_bfloat16 v){ return __bfloat162float(v); }
__device__ __forceinline__ __hip_bfloat16 f2bf(float v){ return __float2bfloat16(v); }
__device__ __forceinline__ float sigmoidf_(float x){ return 1.0f/(1.0f + __expf(-x)); }
__device__ __forceinline__ float tanhf_(float x){ float e = __expf(2.f*x); return 1.f - 2.f/(e + 1.f); }
__device__ __forceinline__ float rdf(const void* p, int i, int f32){
  return f32 ? ((const float*)p)[i] : __bfloat162float(((const __hip_bfloat16*)p)[i]);
}

// ---------------- input dtype detector ----------------
__global__ void k_detect(const void* xraw, int* flag){
  __shared__ int cnt;
  if(threadIdx.x == 0) cnt = 0;
  __syncthreads();
  const unsigned* w = (const unsigned*)xraw;
  int local = 0;
  for(int i = threadIdx.x; i < 4096; i += 256){
    unsigned b = (w[i] >> 8) & 0x7F;
    if(b >= 0x33 && b <= 0x3F) local++;
  }
  atomicAdd(&cnt, local);
  __syncthreads();
  if(threadIdx.x == 0) *flag = (cnt > 2048) ? 0 : 1;   // 1 => fp32 inputs
}

// guard signature: constant 256.0 everywhere (fp32 out)
__global__ void k_fail(float* out, int n){
  int i = blockIdx.x*256 + threadIdx.x;
  if(i < n) out[i] = 256.0f;
}

// ---------------- CSR build ----------------
__global__ void k_count(const int* __restrict__ dst, int* __restrict__ deg){
  int e = blockIdx.x*256 + threadIdx.x;
  if(e < NE){
    unsigned d = (unsigned)dst[e];
    if(d < NN) atomicAdd(&deg[d], 1);
  }
}

__global__ void k_scan(const int* __restrict__ deg, int* __restrict__ offp, int* __restrict__ cursor){
  __shared__ int part[256];
  __shared__ int excl[257];
  const int CH = (NN + 255)/256;
  int tid = threadIdx.x;
  int lo = tid*CH;
  int hi = lo + CH; if(hi > NN) hi = NN;
  int s = 0;
  for(int i=lo;i<hi;i++) s += deg[i];
  part[tid] = s;
  __syncthreads();
  if(tid == 0){
    int run = 0;
    for(int i=0;i<256;i++){ excl[i] = run; run += part[i]; }
    excl[256] = run;
  }
  __syncthreads();
  int run = excl[tid];
  for(int i=lo;i<hi;i++){ offp[i] = run; cursor[i] = run; run += deg[i]; }
  if(tid == 0) offp[NN] = excl[256];
}

__global__ void k_fill(const int* __restrict__ src, const int* __restrict__ dst,
                       int* __restrict__ cursor, int* __restrict__ csr_src){
  int e = blockIdx.x*256 + threadIdx.x;
  if(e >= NE) return;
  unsigned d = (unsigned)dst[e];
  if(d >= NN) return;
  unsigned p = (unsigned)atomicAdd(&cursor[d], 1);
  if(p < NE){
    unsigned sv = (unsigned)src[e];
    csr_src[p] = (sv < NN) ? (int)sv : 0;
  }
}

// ---------------- conversions / weight prep ----------------
__global__ void k_cvt_x(const void* __restrict__ x, const int* __restrict__ flag,
                        __hip_bfloat16* __restrict__ xb){
  int i = blockIdx.x*256 + threadIdx.x;
  int f = *flag;
  if(i < NN*256) xb[i] = f2bf(rdf(x, i, f));
}

__global__ void k_prep(const void* __restrict__ w_src, const void* __restrict__ w_dst,
                       const void* __restrict__ w_hh, const int* __restrict__ flag,
                       __hip_bfloat16* __restrict__ wsrcT, __hip_bfloat16* __restrict__ wdstT,
                       __hip_bfloat16* __restrict__ whhb){
  int tid = blockIdx.x*256 + threadIdx.x;
  int f = *flag;
  if(tid < 131072){
    int l = tid >> 16, r = tid & 65535, o = r >> 8, i = r & 255;
    wsrcT[tid] = f2bf(rdf(w_src, l*65536 + i*256 + o, f));
    wdstT[tid] = f2bf(rdf(w_dst, l*65536 + i*256 + o, f));
  }
  if(tid < 262144) whhb[tid] = f2bf(rdf(w_hh, tid, f));
}

// Wc[g,k] = sum_j Wih[g,j] * mlp_w[j, 1+k]
__global__ void k_prep_wc(const void* __restrict__ wih, const void* __restrict__ mlp_w,
                          const int* __restrict__ flag, __hip_bfloat16* __restrict__ Wc){
  int g = blockIdx.x;
  int k = threadIdx.x;
  int f = *flag;
  float s = 0.f;
  for(int j=0;j<256;j++) s += rdf(wih, g*256+j, f) * rdf(mlp_w, j*257 + 1 + k, f);
  Wc[g*256+k] = f2bf(s);
}

__global__ void k_prep_small(const void* __restrict__ wih, const void* __restrict__ mlp_w,
                             const void* __restrict__ mlp_b,
                             const void* __restrict__ b_ih, const void* __restrict__ b_hh,
                             const void* __restrict__ att, const void* __restrict__ gbias,
                             const void* __restrict__ init_w, const void* __restrict__ init_b,
                             const void* __restrict__ out_w, const void* __restrict__ out_b,
                             const int* __restrict__ flag,
                             float* __restrict__ u, float* __restrict__ bc,
                             float* __restrict__ attf, float* __restrict__ gbiasf,
                             float* __restrict__ initwf, float* __restrict__ outwf,
                             float* __restrict__ sc){
  int g = blockIdx.x*256 + threadIdx.x;
  int f = *flag;
  if(g < 1024){
    float su = 0.f, sb = 0.f;
    for(int j=0;j<256;j++){
      float w = rdf(wih, g*256+j, f);
      su += w * rdf(mlp_w, j*257, f);
      sb += w * rdf(mlp_b, j, f);
    }
    u[g] = su;
    bc[g] = sb + rdf(b_ih, g, f) + rdf(b_hh, g, f);
  }
  if(g < 512){ attf[g] = rdf(att, g, f); gbiasf[g] = rdf(gbias, g, f); }
  if(g < 256){ initwf[g] = rdf(init_w, g, f); outwf[g] = rdf(out_w, g, f); }
  if(g == 0){ sc[0] = rdf(init_b, 0, f); sc[1] = rdf(out_b, 0, f); }
}

// ---------------- NT GEMM (out-of-place): Q[m,n] = sum_k P[m,k]*B[n,k] ----------------
__global__ __launch_bounds__(256) void k_gemm_nt_bf(const __hip_bfloat16* __restrict__ A,
                                                    const __hip_bfloat16* __restrict__ B,
                                                    __hip_bfloat16* __restrict__ Cb){
  int wave = threadIdx.x >> 6;
  int lane = threadIdx.x & 63;
  int l16 = lane & 15, quad = lane >> 4, quad8 = quad*8;
  int mBase = blockIdx.x*64 + wave*16;
  int nBase = blockIdx.y*64;
  int arow = mBase + l16; if(arow >= NN) arow = NN-1;
  const __hip_bfloat16* aptr = A + (size_t)arow*256 + quad8;
  float4v acc[4];
  #pragma unroll
  for(int nt=0;nt<4;nt++){ acc[nt][0]=0.f; acc[nt][1]=0.f; acc[nt][2]=0.f; acc[nt][3]=0.f; }
  for(int k0=0;k0<256;k0+=32){
    bf16x8 a = LD8(aptr + k0);
    #pragma unroll
    for(int nt=0;nt<4;nt++){
      const __hip_bfloat16* bptr = B + (size_t)(nBase + nt*16 + l16)*256 + k0 + quad8;
      acc[nt] = MFMA16(a, LD8(bptr), acc[nt]);
    }
  }
  #pragma unroll
  for(int nt=0;nt<4;nt++){
    int col = nBase + nt*16 + l16;
    #pragma unroll
    for(int r=0;r<4;r++){
      int row = mBase + quad*4 + r;
      if(row < NN) Cb[(size_t)row*256 + col] = f2bf(acc[nt][r]);
    }
  }
}

// ---------------- in-place NT GEMM: P = P@B^T (LDS-staged A; row-exclusive blocks) ----
__global__ __launch_bounds__(256) void k_gemm_inplace(__hip_bfloat16* __restrict__ P,
                                                      const __hip_bfloat16* __restrict__ B){
  __shared__ __hip_bfloat16 sA[64*264];
  int tid = threadIdx.x;
  int mBase = blockIdx.x*64;
  {
    int r = tid >> 2;
    int c0 = (tid & 3)*64;
    int grow = mBase + r; if(grow >= NN) grow = NN-1;
    const __hip_bfloat16* srcp = P + (size_t)grow*256 + c0;
    #pragma unroll
    for(int j=0;j<8;j++) *(bf16x8*)(&sA[r*264 + c0 + j*8]) = LD8(srcp + j*8);
  }
  __syncthreads();
  int w = tid>>6, lane = tid&63, l16 = lane&15, quad = lane>>4, quad8 = quad*8;
  const __hip_bfloat16* arow = &sA[(w*16 + l16)*264 + quad8];
  float4v acc[16];
  #pragma unroll
  for(int nt=0;nt<16;nt++){ acc[nt][0]=0.f; acc[nt][1]=0.f; acc[nt][2]=0.f; acc[nt][3]=0.f; }
  for(int k0=0;k0<256;k0+=32){
    bf16x8 a = *(const bf16x8*)(arow + k0);
    #pragma unroll
    for(int nt=0;nt<16;nt++)
      acc[nt] = MFMA16(a, LD8(B + (size_t)(nt*16+l16)*256 + k0 + quad8), acc[nt]);
  }
  #pragma unroll
  for(int nt=0;nt<16;nt++){
    int col = nt*16 + l16;
    #pragma unroll
    for(int r=0;r<4;r++){
      int row = mBase + w*16 + quad*4 + r;
      if(row < NN) P[(size_t)row*256 + col] = f2bf(acc[nt][r]);
    }
  }
}

// ---------------- fused GAT edge phase: logits+softmax+aggregate+ELU (per node) ------
__global__ __launch_bounds__(256) void k_node_fused(const __hip_bfloat16* __restrict__ Q,
                                                    __hip_bfloat16* __restrict__ P,
                                                    const int* __restrict__ offp,
                                                    const int* __restrict__ csr_src,
                                                    const float* __restrict__ attf,
                                                    const float* __restrict__ gbiasf){
  __shared__ float slog[DEGMAX*4];
  __shared__ int ssrc[DEGMAX];
  int node = blockIdx.x;
  int tid = threadIdx.x;
  int s0 = offp[node], s1 = offp[node+1];
  if(s0 < 0) s0 = 0; if(s0 > NE) s0 = NE;
  if(s1 < s0) s1 = s0; if(s1 > NE) s1 = NE;
  int deg = s1 - s0; if(deg > DEGMAX) deg = DEGMAX;
  if(tid < deg){
    unsigned sv = (unsigned)csr_src[s0 + tid];
    ssrc[tid] = (sv < NN) ? (int)sv : 0;
  }
  __syncthreads();
  int w = tid>>6, lane = tid&63;
  for(int idx=w; idx<deg; idx+=4){
    const __hip_bfloat16* pl = Q + (size_t)ssrc[idx]*256;
    const __hip_bfloat16* pr = P + (size_t)node*256;
    float a[4];
    #pragma unroll
    for(int h=0;h<4;h++){
      float v = bf2f(pl[h*64+lane]) + bf2f(pr[h*64+lane]);
      v = (v > 0.f) ? v : 0.2f*v;
      a[h] = v * attf[h*64+lane];
    }
    #pragma unroll
    for(int h=0;h<4;h++){
      float s = a[h];
      s += __shfl_xor(s, 1, 64);
      s += __shfl_xor(s, 2, 64);
      s += __shfl_xor(s, 4, 64);
      s += __shfl_xor(s, 8, 64);
      s += __shfl_xor(s, 16, 64);
      s += __shfl_xor(s, 32, 64);
      if(lane == 0) slog[idx*4 + h] = s;
    }
  }
  __syncthreads();
  if(tid < 4){
    int h = tid;
    float m = -1e30f;
    for(int i=0;i<deg;i++) m = fmaxf(m, slog[i*4+h]);
    float den = 0.f;
    for(int i=0;i<deg;i++) den += __expf(slog[i*4+h] - m);
    float inv = (den > 0.f) ? 1.f/den : 0.f;
    for(int i=0;i<deg;i++) slog[i*4+h] = __expf(slog[i*4+h] - m)*inv;
  }
  __syncthreads();
  int d = tid, h = d>>6;
  float acc = 0.f;
  for(int i=0;i<deg;i++) acc += slog[i*4+h] * bf2f(Q[(size_t)ssrc[i]*256 + d]);
  acc += gbiasf[d];
  acc = (acc > 0.f) ? acc : (__expf(acc) - 1.f);   // ELU
  P[(size_t)node*256 + d] = f2bf(acc);
}

// ---------------- persistent LSTM: 512 threads (8 waves), 48 rows/block --------------
// r14 evidence: per-block-step time (~25us) independent of M -> bound by the per-wave
// Whh load stream (L2 hot-line camping; all blocks barrier-synced on same lines) and
// dispatch rounds (1 blk/CU). This round: (1) phase = (blockIdx>>3)&7 so blocks on the
// SAME XCD get different k-phases (r14's blockIdx&7 gave same-XCD blocks identical
// phase - useless); (2) M=48 -> 417 blocks = 2 dispatch rounds (was 3), 3x B-reuse.
// acc = 24 tiles (96 AGPR) + ~110 VGPR fits (512,2)'s 256 budget; unroll 2 kept.
__global__ __launch_bounds__(512, 2) void k_lstm12(const __hip_bfloat16* __restrict__ ctx,
                                                   const __hip_bfloat16* __restrict__ Wc,
                                                   const __hip_bfloat16* __restrict__ Whh,
                                                   const float* __restrict__ u_vec,
                                                   const float* __restrict__ bc_vec,
                                                   const float* __restrict__ initwf,
                                                   const float* __restrict__ outwf,
                                                   const float* __restrict__ sc,
                                                   float* __restrict__ out){
  __shared__ __hip_bfloat16 sgx[MR*SGXP];    // 98.7KB: GX+bc, [row][gatecol]
  __shared__ __hip_bfloat16 sh[MR*264];      // 25.3KB h tile (bank-padded)
  __shared__ float spart[512];               // init-reduction scratch
  __shared__ float spartw[MR*8];             // per-wave out-projection partials
  __shared__ float sprev[MR];
  int tid = threadIdx.x;
  int mBase = blockIdx.x*MR;                 // 417*48 = 20016 >= NN (tail guarded)
  int cs = tid>>6, lane = tid&63, l16 = lane&15, quad = lane>>4, quad8 = quad*8;
  int phase = (blockIdx.x >> 3) & 7;         // same-XCD blocks get different phases
  // h0 = ctx rows (two passes of 32 rows)
  #pragma unroll
  for(int p=0;p<2;p++){
    int r = p*32 + (tid >> 4);
    if(r < MR){
      int grow = mBase + r; if(grow >= NN) grow = NN-1;
      int c0 = (tid & 15)*16;
      const __hip_bfloat16* srcp = ctx + (size_t)grow*256 + c0;
      *(bf16x8*)(&sh[r*264 + c0])     = LD8(srcp);
      *(bf16x8*)(&sh[r*264 + c0 + 8]) = LD8(srcp + 8);
    }
  }
  __syncthreads();
  // prev0 = ctx @ init_w + init_b  (two passes of 32 rows)
  #pragma unroll
  for(int p=0;p<2;p++){
    int r = p*32 + (tid >> 4);
    int c0 = (tid & 15)*16;
    float part = 0.f;
    if(r < MR){
      #pragma unroll
      for(int j=0;j<16;j++) part += bf2f(sh[r*264 + c0 + j]) * initwf[c0 + j];
    }
    spart[tid] = part;
    __syncthreads();
    if(tid < 32 && p*32 + tid < MR){
      float s = 0.f;
      #pragma unroll
      for(int j=0;j<16;j++) s += spart[tid*16 + j];
      sprev[p*32 + tid] = s + sc[0];
    }
    __syncthreads();
  }
  // per-thread constants: this wave's 32-col slab, 4 gates
  float ureg[8], owreg[2];
  #pragma unroll
  for(int g=0;g<4;g++)
    #pragma unroll
    for(int tc=0;tc<2;tc++) ureg[g*2+tc] = u_vec[g*256 + cs*32 + tc*16 + l16];
  #pragma unroll
  for(int tc=0;tc<2;tc++) owreg[tc] = outwf[cs*32 + tc*16 + l16];
  float outb = sc[1];
  // GX phase: acc = ctx@Wc^T (4 gates x 32 cols x 3 row-tiles), +bc -> sgx
  {
    float4v acc[24];
    #pragma unroll
    for(int nt=0;nt<24;nt++){ acc[nt][0]=0.f; acc[nt][1]=0.f; acc[nt][2]=0.f; acc[nt][3]=0.f; }
    #pragma unroll 2
    for(int ki=0;ki<8;ki++){
      int k0 = ((ki + phase) & 7)*32;
      bf16x8 a0 = *(const bf16x8*)(&sh[l16*264 + k0 + quad8]);
      bf16x8 a1 = *(const bf16x8*)(&sh[(16 + l16)*264 + k0 + quad8]);
      bf16x8 a2 = *(const bf16x8*)(&sh[(32 + l16)*264 + k0 + quad8]);
      #pragma unroll
      for(int nt=0;nt<8;nt++){
        int brow = (nt>>1)*256 + cs*32 + (nt&1)*16 + l16;
        bf16x8 b = LD8(Wc + (size_t)brow*256 + k0 + quad8);
        acc[nt]    = MFMA16(a0, b, acc[nt]);
        acc[8+nt]  = MFMA16(a1, b, acc[8+nt]);
        acc[16+nt] = MFMA16(a2, b, acc[16+nt]);
      }
    }
    #pragma unroll
    for(int rt=0;rt<3;rt++)
      #pragma unroll
      for(int nt=0;nt<8;nt++){
        int gc = (nt>>1)*256 + cs*32 + (nt&1)*16 + l16;
        float bcv = bc_vec[gc];
        #pragma unroll
        for(int r=0;r<4;r++)
          sgx[(rt*16 + quad*4 + r)*SGXP + gc] = f2bf(acc[rt*8+nt][r] + bcv);
      }
  }
  __syncthreads();   // sgx + sprev visible
  float creg[24];    // idx rt*8 + tc*4 + r
  #pragma unroll
  for(int i=0;i<24;i++) creg[i] = 0.f;
  for(int step=0; step<TOUT; step++){
    // (a) gates GEMM: acc[rt*8 + g*2 + tc] = h @ Whh^T slab; B reused across 3 rt
    float4v acc[24];
    #pragma unroll
    for(int nt=0;nt<24;nt++){ acc[nt][0]=0.f; acc[nt][1]=0.f; acc[nt][2]=0.f; acc[nt][3]=0.f; }
    #pragma unroll 2
    for(int ki=0;ki<8;ki++){
      int k0 = ((ki + phase) & 7)*32;
      bf16x8 a0 = *(const bf16x8*)(&sh[l16*264 + k0 + quad8]);
      bf16x8 a1 = *(const bf16x8*)(&sh[(16 + l16)*264 + k0 + quad8]);
      bf16x8 a2 = *(const bf16x8*)(&sh[(32 + l16)*264 + k0 + quad8]);
      #pragma unroll
      for(int nt=0;nt<8;nt++){
        int brow = (nt>>1)*256 + cs*32 + (nt&1)*16 + l16;
        bf16x8 b = LD8(Whh + (size_t)brow*256 + k0 + quad8);
        acc[nt]    = MFMA16(a0, b, acc[nt]);
        acc[8+nt]  = MFMA16(a1, b, acc[8+nt]);
        acc[16+nt] = MFMA16(a2, b, acc[16+nt]);
      }
    }
    __syncthreads();   // S1: all sh reads done; sprev (from prev step) visible
    // (b) in-register activation + h write + out-projection partials
    float hsum[12];
    #pragma unroll
    for(int i=0;i<12;i++) hsum[i] = 0.f;
    #pragma unroll
    for(int rt=0;rt<3;rt++)
      #pragma unroll
      for(int tc=0;tc<2;tc++){
        int col = cs*32 + tc*16 + l16;
        #pragma unroll
        for(int r=0;r<4;r++){
          int row = rt*16 + quad*4 + r;
          float p = sprev[row];
          float g0 = acc[rt*8 + tc][r]     + bf2f(sgx[row*SGXP + col])       + p*ureg[tc];
          float g1 = acc[rt*8 + 2 + tc][r] + bf2f(sgx[row*SGXP + 256 + col]) + p*ureg[2+tc];
          float g2 = acc[rt*8 + 4 + tc][r] + bf2f(sgx[row*SGXP + 512 + col]) + p*ureg[4+tc];
          float g3 = acc[rt*8 + 6 + tc][r] + bf2f(sgx[row*SGXP + 768 + col]) + p*ureg[6+tc];
          float iv = sigmoidf_(g0), fv = sigmoidf_(g1);
          float gv = tanhf_(g2),    ov = sigmoidf_(g3);
          float cn = fv*creg[rt*8 + tc*4 + r] + iv*gv;
          creg[rt*8 + tc*4 + r] = cn;
          float hn = ov * tanhf_(cn);
          sh[row*264 + col] = f2bf(hn);
          hsum[rt*4 + r] += hn * owreg[tc];
        }
      }
    #pragma unroll
    for(int rr=0;rr<12;rr++){
      hsum[rr] += __shfl_xor(hsum[rr], 1, 64);
      hsum[rr] += __shfl_xor(hsum[rr], 2, 64);
      hsum[rr] += __shfl_xor(hsum[rr], 4, 64);
      hsum[rr] += __shfl_xor(hsum[rr], 8, 64);
    }
    if(l16 == 0){
      #pragma unroll
      for(int rt=0;rt<3;rt++)
        #pragma unroll
        for(int r=0;r<4;r++)
          spartw[(rt*16 + quad*4 + r)*8 + cs] = hsum[rt*4 + r];
    }
    __syncthreads();   // S2: sh writes + spartw visible
    if(tid < MR){
      float s = outb;
      #pragma unroll
      for(int c=0;c<8;c++) s += spartw[tid*8 + c];
      sprev[tid] = s;
      int row = mBase + tid;
      if(row < NN) out[(size_t)row*TOUT + step] = s;
    }
    // next S1 makes sprev visible before next activation
  }
}

// ---------------- launch ----------------
extern "C" void kernel_launch(void* const* d_in, const int* in_sizes, int n_in,
                              void* d_out, int out_size, void* d_ws, size_t ws_size,
                              hipStream_t stream){
  const void* x      = d_in[0];
  const int*  ei     = (const int*)d_in[1];
  const void* w_src  = d_in[2];
  const void* w_dst  = d_in[3];
  const void* att    = d_in[4];
  const void* gbias  = d_in[5];
  const void* mlp_w  = d_in[6];
  const void* mlp_b  = d_in[7];
  const void* w_ih   = d_in[8];
  const void* w_hh   = d_in[9];
  const void* b_ih   = d_in[10];
  const void* b_hh   = d_in[11];
  const void* init_w = d_in[12];
  const void* init_b = d_in[13];
  const void* out_w  = d_in[14];
  const void* out_b  = d_in[15];
  float* out = (float*)d_out;
  const int* srcp = ei;
  const int* dstp = ei + NE;
  (void)in_sizes; (void)n_in;

  char* ws = (char*)d_ws;
  size_t off = 0;
  auto alloc = [&](size_t bytes)->void*{
    void* p = ws + off;
    off += (bytes + 255) & ~(size_t)255;
    return p;
  };
  __hip_bfloat16* P = (__hip_bfloat16*)alloc((size_t)NN*256*2);  // x -> xr -> layer out -> ctx
  __hip_bfloat16* Q = (__hip_bfloat16*)alloc((size_t)NN*256*2);  // xl per layer
  int* deg      = (int*)alloc((size_t)NN*4);
  int* offp     = (int*)alloc((size_t)(NN+1)*4);
  int* cursor   = (int*)alloc((size_t)NN*4);
  int* csr_src  = (int*)alloc((size_t)NE*4);
  __hip_bfloat16* wsrcT = (__hip_bfloat16*)alloc((size_t)131072*2);
  __hip_bfloat16* wdstT = (__hip_bfloat16*)alloc((size_t)131072*2);
  __hip_bfloat16* whhb  = (__hip_bfloat16*)alloc((size_t)262144*2);
  __hip_bfloat16* Wc    = (__hip_bfloat16*)alloc((size_t)262144*2);
  float* u_vec  = (float*)alloc(1024*4);
  float* bc_vec = (float*)alloc(1024*4);
  float* attf   = (float*)alloc(512*4);
  float* gbiasf = (float*)alloc(512*4);
  float* initwf = (float*)alloc(256*4);
  float* outwf  = (float*)alloc(256*4);
  float* sc     = (float*)alloc(2*4);
  int*   flag   = (int*)alloc(4);
  // total ~23.6 MB

  if(off > ws_size){
    k_fail<<<(out_size + 255)/256, 256, 0, stream>>>(out, out_size);
    return;
  }

  // dtype detect + CSR + prep
  k_detect<<<1, 256, 0, stream>>>(x, flag);
  hipMemsetAsync(deg, 0, (size_t)NN*4, stream);
  hipMemsetAsync(csr_src, 0xFF, (size_t)NE*4, stream);
  k_count<<<NE/256, 256, 0, stream>>>(dstp, deg);
  k_scan<<<1, 256, 0, stream>>>(deg, offp, cursor);
  k_fill<<<NE/256, 256, 0, stream>>>(srcp, dstp, cursor, csr_src);
  k_cvt_x<<<NN, 256, 0, stream>>>(x, flag, P);
  k_prep<<<1024, 256, 0, stream>>>(w_src, w_dst, w_hh, flag, wsrcT, wdstT, whhb);
  k_prep_wc<<<1024, 256, 0, stream>>>(w_ih, mlp_w, flag, Wc);
  k_prep_small<<<4, 256, 0, stream>>>(w_ih, mlp_w, mlp_b, b_ih, b_hh, att, gbias,
                                      init_w, init_b, out_w, out_b, flag,
                                      u_vec, bc_vec, attf, gbiasf, initwf, outwf, sc);

  // GAT layers: Q = P@Wsrc^T (xl); P = P@Wdst^T in-place (xr); fused edge phase -> P
  dim3 g64(313, 4);
  for(int l=0;l<2;l++){
    k_gemm_nt_bf<<<g64, 256, 0, stream>>>(P, wsrcT + l*65536, Q);
    k_gemm_inplace<<<313, 256, 0, stream>>>(P, wdstT + l*65536);
    k_node_fused<<<NN, 256, 0, stream>>>(Q, P, offp, csr_src, attf + l*256, gbiasf + l*256);
  }

  // persistent LSTM decoder: M=48, 2 dispatch rounds, XCD-aware k-phase
  k_lstm12<<<NBLK, 512, 0, stream>>>(P, Wc, whhb, u_vec, bc_vec, initwf, outwf, sc, out);
}

// Round 16
// 1244.055 us; speedup vs baseline: 2.0928x; 1.0033x over previous
//
#include <hip/hip_runtime.h>
#include <hip/hip_bf16.h>

#define NN 20000
#define NE 320000
#define TOUT 12
#define DEGMAX 96
#define SGXP 1028   // sgx row stride (bf16): quads hit disjoint bank groups
#define MR 48       // rows per LSTM block (3 row-tiles of 16)
#define NBLK 417    // ceil(20000/48)
#define WCP 262144  // elements per weight copy (1024x256)

typedef __bf16 bf16x8 __attribute__((ext_vector_type(8)));
typedef float float4v __attribute__((ext_vector_type(4)));

#define LD8(p) (*(const bf16x8*)(p))
#define MFMA16(a,b,c) __builtin_amdgcn_mfma_f32_16x16x32_bf16((a),(b),(c),0,0,0)

__device__ __forceinline__ float bf2f(const __hip_bfloat16 v){ return __bfloat162float(v); }
__device__ __forceinline__ __hip_bfloat16 f2bf(float v){ return __float2bfloat16(v); }
__device__ __forceinline__ float sigmoidf_(float x){ return 1.0f/(1.0f + __expf(-x)); }
__device__ __forceinline__ float tanhf_(float x){ float e = __expf(2.f*x); return 1.f - 2.f/(e + 1.f); }
__device__ __forceinline__ float rdf(const void* p, int i, int f32){
  return f32 ? ((const float*)p)[i] : __bfloat162float(((const __hip_bfloat16*)p)[i]);
}

// ---------------- input dtype detector ----------------
__global__ void k_detect(const void* xraw, int* flag){
  __shared__ int cnt;
  if(threadIdx.x == 0) cnt = 0;
  __syncthreads();
  const unsigned* w = (const unsigned*)xraw;
  int local = 0;
  for(int i = threadIdx.x; i < 4096; i += 256){
    unsigned b = (w[i] >> 8) & 0x7F;
    if(b >= 0x33 && b <= 0x3F) local++;
  }
  atomicAdd(&cnt, local);
  __syncthreads();
  if(threadIdx.x == 0) *flag = (cnt > 2048) ? 0 : 1;   // 1 => fp32 inputs
}

// guard signature: constant 256.0 everywhere (fp32 out)
__global__ void k_fail(float* out, int n){
  int i = blockIdx.x*256 + threadIdx.x;
  if(i < n) out[i] = 256.0f;
}

// ---------------- CSR build ----------------
__global__ void k_count(const int* __restrict__ dst, int* __restrict__ deg){
  int e = blockIdx.x*256 + threadIdx.x;
  if(e < NE){
    unsigned d = (unsigned)dst[e];
    if(d < NN) atomicAdd(&deg[d], 1);
  }
}

__global__ void k_scan(const int* __restrict__ deg, int* __restrict__ offp, int* __restrict__ cursor){
  __shared__ int part[256];
  __shared__ int excl[257];
  const int CH = (NN + 255)/256;
  int tid = threadIdx.x;
  int lo = tid*CH;
  int hi = lo + CH; if(hi > NN) hi = NN;
  int s = 0;
  for(int i=lo;i<hi;i++) s += deg[i];
  part[tid] = s;
  __syncthreads();
  if(tid == 0){
    int run = 0;
    for(int i=0;i<256;i++){ excl[i] = run; run += part[i]; }
    excl[256] = run;
  }
  __syncthreads();
  int run = excl[tid];
  for(int i=lo;i<hi;i++){ offp[i] = run; cursor[i] = run; run += deg[i]; }
  if(tid == 0) offp[NN] = excl[256];
}

__global__ void k_fill(const int* __restrict__ src, const int* __restrict__ dst,
                       int* __restrict__ cursor, int* __restrict__ csr_src){
  int e = blockIdx.x*256 + threadIdx.x;
  if(e >= NE) return;
  unsigned d = (unsigned)dst[e];
  if(d >= NN) return;
  unsigned p = (unsigned)atomicAdd(&cursor[d], 1);
  if(p < NE){
    unsigned sv = (unsigned)src[e];
    csr_src[p] = (sv < NN) ? (int)sv : 0;
  }
}

// ---------------- conversions / weight prep ----------------
__global__ void k_cvt_x(const void* __restrict__ x, const int* __restrict__ flag,
                        __hip_bfloat16* __restrict__ xb){
  int i = blockIdx.x*256 + threadIdx.x;
  int f = *flag;
  if(i < NN*256) xb[i] = f2bf(rdf(x, i, f));
}

__global__ void k_prep(const void* __restrict__ w_src, const void* __restrict__ w_dst,
                       const void* __restrict__ w_hh, const int* __restrict__ flag,
                       __hip_bfloat16* __restrict__ wsrcT, __hip_bfloat16* __restrict__ wdstT,
                       __hip_bfloat16* __restrict__ whh4){
  int tid = blockIdx.x*256 + threadIdx.x;
  int f = *flag;
  if(tid < 131072){
    int l = tid >> 16, r = tid & 65535, o = r >> 8, i = r & 255;
    wsrcT[tid] = f2bf(rdf(w_src, l*65536 + i*256 + o, f));
    wdstT[tid] = f2bf(rdf(w_dst, l*65536 + i*256 + o, f));
  }
  if(tid < WCP){
    __hip_bfloat16 v = f2bf(rdf(w_hh, tid, f));
    #pragma unroll
    for(int c=0;c<4;c++) whh4[c*WCP + tid] = v;
  }
}

// Wc[g,k] = sum_j Wih[g,j] * mlp_w[j, 1+k]  (replicated 4x)
__global__ void k_prep_wc(const void* __restrict__ wih, const void* __restrict__ mlp_w,
                          const int* __restrict__ flag, __hip_bfloat16* __restrict__ Wc4){
  int g = blockIdx.x;
  int k = threadIdx.x;
  int f = *flag;
  float s = 0.f;
  for(int j=0;j<256;j++) s += rdf(wih, g*256+j, f) * rdf(mlp_w, j*257 + 1 + k, f);
  __hip_bfloat16 v = f2bf(s);
  #pragma unroll
  for(int c=0;c<4;c++) Wc4[c*WCP + g*256 + k] = v;
}

__global__ void k_prep_small(const void* __restrict__ wih, const void* __restrict__ mlp_w,
                             const void* __restrict__ mlp_b,
                             const void* __restrict__ b_ih, const void* __restrict__ b_hh,
                             const void* __restrict__ att, const void* __restrict__ gbias,
                             const void* __restrict__ init_w, const void* __restrict__ init_b,
                             const void* __restrict__ out_w, const void* __restrict__ out_b,
                             const int* __restrict__ flag,
                             float* __restrict__ u, float* __restrict__ bc,
                             float* __restrict__ attf, float* __restrict__ gbiasf,
                             float* __restrict__ initwf, float* __restrict__ outwf,
                             float* __restrict__ sc){
  int g = blockIdx.x*256 + threadIdx.x;
  int f = *flag;
  if(g < 1024){
    float su = 0.f, sb = 0.f;
    for(int j=0;j<256;j++){
      float w = rdf(wih, g*256+j, f);
      su += w * rdf(mlp_w, j*257, f);
      sb += w * rdf(mlp_b, j, f);
    }
    u[g] = su;
    bc[g] = sb + rdf(b_ih, g, f) + rdf(b_hh, g, f);
  }
  if(g < 512){ attf[g] = rdf(att, g, f); gbiasf[g] = rdf(gbias, g, f); }
  if(g < 256){ initwf[g] = rdf(init_w, g, f); outwf[g] = rdf(out_w, g, f); }
  if(g == 0){ sc[0] = rdf(init_b, 0, f); sc[1] = rdf(out_b, 0, f); }
}

// ---------------- NT GEMM (out-of-place): Q[m,n] = sum_k P[m,k]*B[n,k] ----------------
__global__ __launch_bounds__(256) void k_gemm_nt_bf(const __hip_bfloat16* __restrict__ A,
                                                    const __hip_bfloat16* __restrict__ B,
                                                    __hip_bfloat16* __restrict__ Cb){
  int wave = threadIdx.x >> 6;
  int lane = threadIdx.x & 63;
  int l16 = lane & 15, quad = lane >> 4, quad8 = quad*8;
  int mBase = blockIdx.x*64 + wave*16;
  int nBase = blockIdx.y*64;
  int arow = mBase + l16; if(arow >= NN) arow = NN-1;
  const __hip_bfloat16* aptr = A + (size_t)arow*256 + quad8;
  float4v acc[4];
  #pragma unroll
  for(int nt=0;nt<4;nt++){ acc[nt][0]=0.f; acc[nt][1]=0.f; acc[nt][2]=0.f; acc[nt][3]=0.f; }
  for(int k0=0;k0<256;k0+=32){
    bf16x8 a = LD8(aptr + k0);
    #pragma unroll
    for(int nt=0;nt<4;nt++){
      const __hip_bfloat16* bptr = B + (size_t)(nBase + nt*16 + l16)*256 + k0 + quad8;
      acc[nt] = MFMA16(a, LD8(bptr), acc[nt]);
    }
  }
  #pragma unroll
  for(int nt=0;nt<4;nt++){
    int col = nBase + nt*16 + l16;
    #pragma unroll
    for(int r=0;r<4;r++){
      int row = mBase + quad*4 + r;
      if(row < NN) Cb[(size_t)row*256 + col] = f2bf(acc[nt][r]);
    }
  }
}

// ---------------- in-place NT GEMM: P = P@B^T (LDS-staged A; row-exclusive blocks) ----
__global__ __launch_bounds__(256) void k_gemm_inplace(__hip_bfloat16* __restrict__ P,
                                                      const __hip_bfloat16* __restrict__ B){
  __shared__ __hip_bfloat16 sA[64*264];
  int tid = threadIdx.x;
  int mBase = blockIdx.x*64;
  {
    int r = tid >> 2;
    int c0 = (tid & 3)*64;
    int grow = mBase + r; if(grow >= NN) grow = NN-1;
    const __hip_bfloat16* srcp = P + (size_t)grow*256 + c0;
    #pragma unroll
    for(int j=0;j<8;j++) *(bf16x8*)(&sA[r*264 + c0 + j*8]) = LD8(srcp + j*8);
  }
  __syncthreads();
  int w = tid>>6, lane = tid&63, l16 = lane&15, quad = lane>>4, quad8 = quad*8;
  const __hip_bfloat16* arow = &sA[(w*16 + l16)*264 + quad8];
  float4v acc[16];
  #pragma unroll
  for(int nt=0;nt<16;nt++){ acc[nt][0]=0.f; acc[nt][1]=0.f; acc[nt][2]=0.f; acc[nt][3]=0.f; }
  for(int k0=0;k0<256;k0+=32){
    bf16x8 a = *(const bf16x8*)(arow + k0);
    #pragma unroll
    for(int nt=0;nt<16;nt++)
      acc[nt] = MFMA16(a, LD8(B + (size_t)(nt*16+l16)*256 + k0 + quad8), acc[nt]);
  }
  #pragma unroll
  for(int nt=0;nt<16;nt++){
    int col = nt*16 + l16;
    #pragma unroll
    for(int r=0;r<4;r++){
      int row = mBase + w*16 + quad*4 + r;
      if(row < NN) P[(size_t)row*256 + col] = f2bf(acc[nt][r]);
    }
  }
}

// ---------------- fused GAT edge phase: logits+softmax+aggregate+ELU (per node) ------
__global__ __launch_bounds__(256) void k_node_fused(const __hip_bfloat16* __restrict__ Q,
                                                    __hip_bfloat16* __restrict__ P,
                                                    const int* __restrict__ offp,
                                                    const int* __restrict__ csr_src,
                                                    const float* __restrict__ attf,
                                                    const float* __restrict__ gbiasf){
  __shared__ float slog[DEGMAX*4];
  __shared__ int ssrc[DEGMAX];
  int node = blockIdx.x;
  int tid = threadIdx.x;
  int s0 = offp[node], s1 = offp[node+1];
  if(s0 < 0) s0 = 0; if(s0 > NE) s0 = NE;
  if(s1 < s0) s1 = s0; if(s1 > NE) s1 = NE;
  int deg = s1 - s0; if(deg > DEGMAX) deg = DEGMAX;
  if(tid < deg){
    unsigned sv = (unsigned)csr_src[s0 + tid];
    ssrc[tid] = (sv < NN) ? (int)sv : 0;
  }
  __syncthreads();
  int w = tid>>6, lane = tid&63;
  for(int idx=w; idx<deg; idx+=4){
    const __hip_bfloat16* pl = Q + (size_t)ssrc[idx]*256;
    const __hip_bfloat16* pr = P + (size_t)node*256;
    float a[4];
    #pragma unroll
    for(int h=0;h<4;h++){
      float v = bf2f(pl[h*64+lane]) + bf2f(pr[h*64+lane]);
      v = (v > 0.f) ? v : 0.2f*v;
      a[h] = v * attf[h*64+lane];
    }
    #pragma unroll
    for(int h=0;h<4;h++){
      float s = a[h];
      s += __shfl_xor(s, 1, 64);
      s += __shfl_xor(s, 2, 64);
      s += __shfl_xor(s, 4, 64);
      s += __shfl_xor(s, 8, 64);
      s += __shfl_xor(s, 16, 64);
      s += __shfl_xor(s, 32, 64);
      if(lane == 0) slog[idx*4 + h] = s;
    }
  }
  __syncthreads();
  if(tid < 4){
    int h = tid;
    float m = -1e30f;
    for(int i=0;i<deg;i++) m = fmaxf(m, slog[i*4+h]);
    float den = 0.f;
    for(int i=0;i<deg;i++) den += __expf(slog[i*4+h] - m);
    float inv = (den > 0.f) ? 1.f/den : 0.f;
    for(int i=0;i<deg;i++) slog[i*4+h] = __expf(slog[i*4+h] - m)*inv;
  }
  __syncthreads();
  int d = tid, h = d>>6;
  float acc = 0.f;
  for(int i=0;i<deg;i++) acc += slog[i*4+h] * bf2f(Q[(size_t)ssrc[i]*256 + d]);
  acc += gbiasf[d];
  acc = (acc > 0.f) ? acc : (__expf(acc) - 1.f);   // ELU
  P[(size_t)node*256 + d] = f2bf(acc);
}

// ---------------- persistent LSTM: 512 threads (8 waves), 48 rows/block --------------
// r15 residual: per-step time 26.7us (~64K cyc) vs ~2-3K cyc in-block critical path ->
// device-wide L2 hot-line camping on the single shared Whh image. This round: Whh/Wc
// replicated 4x; copy = (blockIdx>>3)&3, phase = (blockIdx>>5)&7 -> all 32 CUs on an
// XCD have a unique (copy,phase) pair -> no same-address lockstep. 4 copies = 2MB,
// fits 4MB/XCD L2. Everything else identical to r15.
__global__ __launch_bounds__(512, 2) void k_lstm12(const __hip_bfloat16* __restrict__ ctx,
                                                   const __hip_bfloat16* __restrict__ Wc4,
                                                   const __hip_bfloat16* __restrict__ Whh4,
                                                   const float* __restrict__ u_vec,
                                                   const float* __restrict__ bc_vec,
                                                   const float* __restrict__ initwf,
                                                   const float* __restrict__ outwf,
                                                   const float* __restrict__ sc,
                                                   float* __restrict__ out){
  __shared__ __hip_bfloat16 sgx[MR*SGXP];    // 98.7KB: GX+bc, [row][gatecol]
  __shared__ __hip_bfloat16 sh[MR*264];      // 25.3KB h tile (bank-padded)
  __shared__ float spart[512];               // init-reduction scratch
  __shared__ float spartw[MR*8];             // per-wave out-projection partials
  __shared__ float sprev[MR];
  int tid = threadIdx.x;
  int mBase = blockIdx.x*MR;                 // 417*48 = 20016 >= NN (tail guarded)
  int cs = tid>>6, lane = tid&63, l16 = lane&15, quad = lane>>4, quad8 = quad*8;
  int q = blockIdx.x >> 3;                   // per-XCD block sequence
  int copy = q & 3;
  int phase = (q >> 2) & 7;
  const __hip_bfloat16* WcB  = Wc4  + (size_t)copy*WCP;
  const __hip_bfloat16* WhhB = Whh4 + (size_t)copy*WCP;
  // h0 = ctx rows (two passes of 32 rows)
  #pragma unroll
  for(int p=0;p<2;p++){
    int r = p*32 + (tid >> 4);
    if(r < MR){
      int grow = mBase + r; if(grow >= NN) grow = NN-1;
      int c0 = (tid & 15)*16;
      const __hip_bfloat16* srcp = ctx + (size_t)grow*256 + c0;
      *(bf16x8*)(&sh[r*264 + c0])     = LD8(srcp);
      *(bf16x8*)(&sh[r*264 + c0 + 8]) = LD8(srcp + 8);
    }
  }
  __syncthreads();
  // prev0 = ctx @ init_w + init_b  (two passes of 32 rows)
  #pragma unroll
  for(int p=0;p<2;p++){
    int r = p*32 + (tid >> 4);
    int c0 = (tid & 15)*16;
    float part = 0.f;
    if(r < MR){
      #pragma unroll
      for(int j=0;j<16;j++) part += bf2f(sh[r*264 + c0 + j]) * initwf[c0 + j];
    }
    spart[tid] = part;
    __syncthreads();
    if(tid < 32 && p*32 + tid < MR){
      float s = 0.f;
      #pragma unroll
      for(int j=0;j<16;j++) s += spart[tid*16 + j];
      sprev[p*32 + tid] = s + sc[0];
    }
    __syncthreads();
  }
  // per-thread constants: this wave's 32-col slab, 4 gates
  float ureg[8], owreg[2];
  #pragma unroll
  for(int g=0;g<4;g++)
    #pragma unroll
    for(int tc=0;tc<2;tc++) ureg[g*2+tc] = u_vec[g*256 + cs*32 + tc*16 + l16];
  #pragma unroll
  for(int tc=0;tc<2;tc++) owreg[tc] = outwf[cs*32 + tc*16 + l16];
  float outb = sc[1];
  // GX phase: acc = ctx@Wc^T (4 gates x 32 cols x 3 row-tiles), +bc -> sgx
  {
    float4v acc[24];
    #pragma unroll
    for(int nt=0;nt<24;nt++){ acc[nt][0]=0.f; acc[nt][1]=0.f; acc[nt][2]=0.f; acc[nt][3]=0.f; }
    #pragma unroll 2
    for(int ki=0;ki<8;ki++){
      int k0 = ((ki + phase) & 7)*32;
      bf16x8 a0 = *(const bf16x8*)(&sh[l16*264 + k0 + quad8]);
      bf16x8 a1 = *(const bf16x8*)(&sh[(16 + l16)*264 + k0 + quad8]);
      bf16x8 a2 = *(const bf16x8*)(&sh[(32 + l16)*264 + k0 + quad8]);
      #pragma unroll
      for(int nt=0;nt<8;nt++){
        int brow = (nt>>1)*256 + cs*32 + (nt&1)*16 + l16;
        bf16x8 b = LD8(WcB + (size_t)brow*256 + k0 + quad8);
        acc[nt]    = MFMA16(a0, b, acc[nt]);
        acc[8+nt]  = MFMA16(a1, b, acc[8+nt]);
        acc[16+nt] = MFMA16(a2, b, acc[16+nt]);
      }
    }
    #pragma unroll
    for(int rt=0;rt<3;rt++)
      #pragma unroll
      for(int nt=0;nt<8;nt++){
        int gc = (nt>>1)*256 + cs*32 + (nt&1)*16 + l16;
        float bcv = bc_vec[gc];
        #pragma unroll
        for(int r=0;r<4;r++)
          sgx[(rt*16 + quad*4 + r)*SGXP + gc] = f2bf(acc[rt*8+nt][r] + bcv);
      }
  }
  __syncthreads();   // sgx + sprev visible
  float creg[24];    // idx rt*8 + tc*4 + r
  #pragma unroll
  for(int i=0;i<24;i++) creg[i] = 0.f;
  for(int step=0; step<TOUT; step++){
    // (a) gates GEMM: acc[rt*8 + g*2 + tc] = h @ Whh^T slab; B reused across 3 rt
    float4v acc[24];
    #pragma unroll
    for(int nt=0;nt<24;nt++){ acc[nt][0]=0.f; acc[nt][1]=0.f; acc[nt][2]=0.f; acc[nt][3]=0.f; }
    #pragma unroll 2
    for(int ki=0;ki<8;ki++){
      int k0 = ((ki + phase) & 7)*32;
      bf16x8 a0 = *(const bf16x8*)(&sh[l16*264 + k0 + quad8]);
      bf16x8 a1 = *(const bf16x8*)(&sh[(16 + l16)*264 + k0 + quad8]);
      bf16x8 a2 = *(const bf16x8*)(&sh[(32 + l16)*264 + k0 + quad8]);
      #pragma unroll
      for(int nt=0;nt<8;nt++){
        int brow = (nt>>1)*256 + cs*32 + (nt&1)*16 + l16;
        bf16x8 b = LD8(WhhB + (size_t)brow*256 + k0 + quad8);
        acc[nt]    = MFMA16(a0, b, acc[nt]);
        acc[8+nt]  = MFMA16(a1, b, acc[8+nt]);
        acc[16+nt] = MFMA16(a2, b, acc[16+nt]);
      }
    }
    __syncthreads();   // S1: all sh reads done; sprev (from prev step) visible
    // (b) in-register activation + h write + out-projection partials
    float hsum[12];
    #pragma unroll
    for(int i=0;i<12;i++) hsum[i] = 0.f;
    #pragma unroll
    for(int rt=0;rt<3;rt++)
      #pragma unroll
      for(int tc=0;tc<2;tc++){
        int col = cs*32 + tc*16 + l16;
        #pragma unroll
        for(int r=0;r<4;r++){
          int row = rt*16 + quad*4 + r;
          float p = sprev[row];
          float g0 = acc[rt*8 + tc][r]     + bf2f(sgx[row*SGXP + col])       + p*ureg[tc];
          float g1 = acc[rt*8 + 2 + tc][r] + bf2f(sgx[row*SGXP + 256 + col]) + p*ureg[2+tc];
          float g2 = acc[rt*8 + 4 + tc][r] + bf2f(sgx[row*SGXP + 512 + col]) + p*ureg[4+tc];
          float g3 = acc[rt*8 + 6 + tc][r] + bf2f(sgx[row*SGXP + 768 + col]) + p*ureg[6+tc];
          float iv = sigmoidf_(g0), fv = sigmoidf_(g1);
          float gv = tanhf_(g2),    ov = sigmoidf_(g3);
          float cn = fv*creg[rt*8 + tc*4 + r] + iv*gv;
          creg[rt*8 + tc*4 + r] = cn;
          float hn = ov * tanhf_(cn);
          sh[row*264 + col] = f2bf(hn);
          hsum[rt*4 + r] += hn * owreg[tc];
        }
      }
    #pragma unroll
    for(int rr=0;rr<12;rr++){
      hsum[rr] += __shfl_xor(hsum[rr], 1, 64);
      hsum[rr] += __shfl_xor(hsum[rr], 2, 64);
      hsum[rr] += __shfl_xor(hsum[rr], 4, 64);
      hsum[rr] += __shfl_xor(hsum[rr], 8, 64);
    }
    if(l16 == 0){
      #pragma unroll
      for(int rt=0;rt<3;rt++)
        #pragma unroll
        for(int r=0;r<4;r++)
          spartw[(rt*16 + quad*4 + r)*8 + cs] = hsum[rt*4 + r];
    }
    __syncthreads();   // S2: sh writes + spartw visible
    if(tid < MR){
      float s = outb;
      #pragma unroll
      for(int c=0;c<8;c++) s += spartw[tid*8 + c];
      sprev[tid] = s;
      int row = mBase + tid;
      if(row < NN) out[(size_t)row*TOUT + step] = s;
    }
    // next S1 makes sprev visible before next activation
  }
}

// ---------------- launch ----------------
extern "C" void kernel_launch(void* const* d_in, const int* in_sizes, int n_in,
                              void* d_out, int out_size, void* d_ws, size_t ws_size,
                              hipStream_t stream){
  const void* x      = d_in[0];
  const int*  ei     = (const int*)d_in[1];
  const void* w_src  = d_in[2];
  const void* w_dst  = d_in[3];
  const void* att    = d_in[4];
  const void* gbias  = d_in[5];
  const void* mlp_w  = d_in[6];
  const void* mlp_b  = d_in[7];
  const void* w_ih   = d_in[8];
  const void* w_hh   = d_in[9];
  const void* b_ih   = d_in[10];
  const void* b_hh   = d_in[11];
  const void* init_w = d_in[12];
  const void* init_b = d_in[13];
  const void* out_w  = d_in[14];
  const void* out_b  = d_in[15];
  float* out = (float*)d_out;
  const int* srcp = ei;
  const int* dstp = ei + NE;
  (void)in_sizes; (void)n_in;

  char* ws = (char*)d_ws;
  size_t off = 0;
  auto alloc = [&](size_t bytes)->void*{
    void* p = ws + off;
    off += (bytes + 255) & ~(size_t)255;
    return p;
  };
  __hip_bfloat16* P = (__hip_bfloat16*)alloc((size_t)NN*256*2);  // x -> xr -> layer out -> ctx
  __hip_bfloat16* Q = (__hip_bfloat16*)alloc((size_t)NN*256*2);  // xl per layer
  int* deg      = (int*)alloc((size_t)NN*4);
  int* offp     = (int*)alloc((size_t)(NN+1)*4);
  int* cursor   = (int*)alloc((size_t)NN*4);
  int* csr_src  = (int*)alloc((size_t)NE*4);
  __hip_bfloat16* wsrcT = (__hip_bfloat16*)alloc((size_t)131072*2);
  __hip_bfloat16* wdstT = (__hip_bfloat16*)alloc((size_t)131072*2);
  __hip_bfloat16* whh4  = (__hip_bfloat16*)alloc((size_t)4*WCP*2);  // 2 MB, 4 copies
  __hip_bfloat16* Wc4   = (__hip_bfloat16*)alloc((size_t)4*WCP*2);  // 2 MB, 4 copies
  float* u_vec  = (float*)alloc(1024*4);
  float* bc_vec = (float*)alloc(1024*4);
  float* attf   = (float*)alloc(512*4);
  float* gbiasf = (float*)alloc(512*4);
  float* initwf = (float*)alloc(256*4);
  float* outwf  = (float*)alloc(256*4);
  float* sc     = (float*)alloc(2*4);
  int*   flag   = (int*)alloc(4);
  // total ~26.6 MB (ws_size >= 64.6 MB proven in r7/r8)

  if(off > ws_size){
    k_fail<<<(out_size + 255)/256, 256, 0, stream>>>(out, out_size);
    return;
  }

  // dtype detect + CSR + prep
  k_detect<<<1, 256, 0, stream>>>(x, flag);
  hipMemsetAsync(deg, 0, (size_t)NN*4, stream);
  hipMemsetAsync(csr_src, 0xFF, (size_t)NE*4, stream);
  k_count<<<NE/256, 256, 0, stream>>>(dstp, deg);
  k_scan<<<1, 256, 0, stream>>>(deg, offp, cursor);
  k_fill<<<NE/256, 256, 0, stream>>>(srcp, dstp, cursor, csr_src);
  k_cvt_x<<<NN, 256, 0, stream>>>(x, flag, P);
  k_prep<<<1024, 256, 0, stream>>>(w_src, w_dst, w_hh, flag, wsrcT, wdstT, whh4);
  k_prep_wc<<<1024, 256, 0, stream>>>(w_ih, mlp_w, flag, Wc4);
  k_prep_small<<<4, 256, 0, stream>>>(w_ih, mlp_w, mlp_b, b_ih, b_hh, att, gbias,
                                      init_w, init_b, out_w, out_b, flag,
                                      u_vec, bc_vec, attf, gbiasf, initwf, outwf, sc);

  // GAT layers: Q = P@Wsrc^T (xl); P = P@Wdst^T in-place (xr); fused edge phase -> P
  dim3 g64(313, 4);
  for(int l=0;l<2;l++){
    k_gemm_nt_bf<<<g64, 256, 0, stream>>>(P, wsrcT + l*65536, Q);
    k_gemm_inplace<<<313, 256, 0, stream>>>(P, wdstT + l*65536);
    k_node_fused<<<NN, 256, 0, stream>>>(Q, P, offp, csr_src, attf + l*256, gbiasf + l*256);
  }

  // persistent LSTM decoder: 4x-replicated weights, per-CU (copy,phase) spread
  k_lstm12<<<NBLK, 512, 0, stream>>>(P, Wc4, whh4, u_vec, bc_vec, initwf, outwf, sc, out);
}

// Round 17
// 927.830 us; speedup vs baseline: 2.8060x; 1.3408x over previous
//
#include <hip/hip_runtime.h>
#include <hip/hip_bf16.h>

#define NN 20000
#define NE 320000
#define TOUT 12
#define DEGMAX 96
#define SGXP 1028   // sgx row stride (bf16): quads hit disjoint bank groups
#define MR 48       // rows per LSTM block (3 row-tiles of 16)
#define NBLK 417    // ceil(20000/48)

typedef __bf16 bf16x8 __attribute__((ext_vector_type(8)));
typedef float float4v __attribute__((ext_vector_type(4)));

#define LD8(p) (*(const bf16x8*)(p))
#define MFMA16(a,b,c) __builtin_amdgcn_mfma_f32_16x16x32_bf16((a),(b),(c),0,0,0)

__device__ __forceinline__ float bf2f(const __hip_bfloat16 v){ return __bfloat162float(v); }
__device__ __forceinline__ __hip_bfloat16 f2bf(float v){ return __float2bfloat16(v); }
__device__ __forceinline__ float sigmoidf_(float x){ return 1.0f/(1.0f + __expf(-x)); }
__device__ __forceinline__ float tanhf_(float x){ float e = __expf(2.f*x); return 1.f - 2.f/(e + 1.f); }
__device__ __forceinline__ float rdf(const void* p, int i, int f32){
  return f32 ? ((const float*)p)[i] : __bfloat162float(((const __hip_bfloat16*)p)[i]);
}

// ---------------- input dtype detector ----------------
__global__ void k_detect(const void* xraw, int* flag){
  __shared__ int cnt;
  if(threadIdx.x == 0) cnt = 0;
  __syncthreads();
  const unsigned* w = (const unsigned*)xraw;
  int local = 0;
  for(int i = threadIdx.x; i < 4096; i += 256){
    unsigned b = (w[i] >> 8) & 0x7F;
    if(b >= 0x33 && b <= 0x3F) local++;
  }
  atomicAdd(&cnt, local);
  __syncthreads();
  if(threadIdx.x == 0) *flag = (cnt > 2048) ? 0 : 1;   // 1 => fp32 inputs
}

// guard signature: constant 256.0 everywhere (fp32 out)
__global__ void k_fail(float* out, int n){
  int i = blockIdx.x*256 + threadIdx.x;
  if(i < n) out[i] = 256.0f;
}

// ---------------- CSR build ----------------
__global__ void k_count(const int* __restrict__ dst, int* __restrict__ deg){
  int e = blockIdx.x*256 + threadIdx.x;
  if(e < NE){
    unsigned d = (unsigned)dst[e];
    if(d < NN) atomicAdd(&deg[d], 1);
  }
}

__global__ void k_scan(const int* __restrict__ deg, int* __restrict__ offp, int* __restrict__ cursor){
  __shared__ int part[256];
  __shared__ int excl[257];
  const int CH = (NN + 255)/256;
  int tid = threadIdx.x;
  int lo = tid*CH;
  int hi = lo + CH; if(hi > NN) hi = NN;
  int s = 0;
  for(int i=lo;i<hi;i++) s += deg[i];
  part[tid] = s;
  __syncthreads();
  if(tid == 0){
    int run = 0;
    for(int i=0;i<256;i++){ excl[i] = run; run += part[i]; }
    excl[256] = run;
  }
  __syncthreads();
  int run = excl[tid];
  for(int i=lo;i<hi;i++){ offp[i] = run; cursor[i] = run; run += deg[i]; }
  if(tid == 0) offp[NN] = excl[256];
}

__global__ void k_fill(const int* __restrict__ src, const int* __restrict__ dst,
                       int* __restrict__ cursor, int* __restrict__ csr_src){
  int e = blockIdx.x*256 + threadIdx.x;
  if(e >= NE) return;
  unsigned d = (unsigned)dst[e];
  if(d >= NN) return;
  unsigned p = (unsigned)atomicAdd(&cursor[d], 1);
  if(p < NE){
    unsigned sv = (unsigned)src[e];
    csr_src[p] = (sv < NN) ? (int)sv : 0;
  }
}

// ---------------- conversions / weight prep ----------------
__global__ void k_cvt_x(const void* __restrict__ x, const int* __restrict__ flag,
                        __hip_bfloat16* __restrict__ xb){
  int i = blockIdx.x*256 + threadIdx.x;
  int f = *flag;
  if(i < NN*256) xb[i] = f2bf(rdf(x, i, f));
}

__global__ void k_prep(const void* __restrict__ w_src, const void* __restrict__ w_dst,
                       const void* __restrict__ w_hh, const int* __restrict__ flag,
                       __hip_bfloat16* __restrict__ wsrcT, __hip_bfloat16* __restrict__ wdstT,
                       __hip_bfloat16* __restrict__ whhp){
  int tid = blockIdx.x*256 + threadIdx.x;
  int f = *flag;
  if(tid < 131072){
    int l = tid >> 16, r = tid & 65535, o = r >> 8, i = r & 255;
    wsrcT[tid] = f2bf(rdf(w_src, l*65536 + i*256 + o, f));
    wdstT[tid] = f2bf(rdf(w_dst, l*65536 + i*256 + o, f));
  }
  if(tid < 262144) whhp[tid] = f2bf(rdf(w_hh, tid, f));
}

// wihb = bf16(Wih); mlpT[k,j] = mlp_w[j, 1+k]
__global__ void k_cvt2(const void* __restrict__ wih, const void* __restrict__ mlp_w,
                       const int* __restrict__ flag,
                       __hip_bfloat16* __restrict__ wihb, __hip_bfloat16* __restrict__ mlpT){
  int i = blockIdx.x*256 + threadIdx.x;
  int f = *flag;
  if(i < 262144) wihb[i] = f2bf(rdf(wih, i, f));
  if(i < 65536){
    int k = i >> 8, j = i & 255;
    mlpT[i] = f2bf(rdf(mlp_w, j*257 + 1 + k, f));
  }
}

// u[g], bc[g] via parallel block reduction (block = g)
__global__ void k_prep_ub(const void* __restrict__ wih, const void* __restrict__ mlp_w,
                          const void* __restrict__ mlp_b,
                          const void* __restrict__ b_ih, const void* __restrict__ b_hh,
                          const int* __restrict__ flag,
                          float* __restrict__ u, float* __restrict__ bc){
  __shared__ float su[256], sb[256];
  int g = blockIdx.x, j = threadIdx.x, f = *flag;
  float w = rdf(wih, g*256 + j, f);
  su[j] = w * rdf(mlp_w, j*257, f);
  sb[j] = w * rdf(mlp_b, j, f);
  __syncthreads();
  for(int s=128; s>0; s>>=1){
    if(j < s){ su[j] += su[j+s]; sb[j] += sb[j+s]; }
    __syncthreads();
  }
  if(j == 0){ u[g] = su[0]; bc[g] = sb[0] + rdf(b_ih, g, f) + rdf(b_hh, g, f); }
}

__global__ void k_prep_small(const void* __restrict__ att, const void* __restrict__ gbias,
                             const void* __restrict__ init_w, const void* __restrict__ init_b,
                             const void* __restrict__ out_w, const void* __restrict__ out_b,
                             const int* __restrict__ flag,
                             float* __restrict__ attf, float* __restrict__ gbiasf,
                             float* __restrict__ initwf, float* __restrict__ outwf,
                             float* __restrict__ sc){
  int g = blockIdx.x*256 + threadIdx.x;
  int f = *flag;
  if(g < 512){ attf[g] = rdf(att, g, f); gbiasf[g] = rdf(gbias, g, f); }
  if(g < 256){ initwf[g] = rdf(init_w, g, f); outwf[g] = rdf(out_w, g, f); }
  if(g == 0){ sc[0] = rdf(init_b, 0, f); sc[1] = rdf(out_b, 0, f); }
}

// pack plain [1024x256] row-major weights into per-wave fragment order:
// P[((cs*8 + kslot)*8 + nt)*512 + lane*8 ..] = W[brow(cs,nt,l16)*256 + kslot*32 + quad*8 ..]
__global__ void k_pack(const __hip_bfloat16* __restrict__ Wpl, const __hip_bfloat16* __restrict__ Wcpl,
                       __hip_bfloat16* __restrict__ WhhP, __hip_bfloat16* __restrict__ WcP){
  int idx = blockIdx.x*256 + threadIdx.x;   // 0..32767
  if(idx >= 32768) return;
  int cs = idx >> 12;
  int kslot = (idx >> 9) & 7;
  int nt = (idx >> 6) & 7;
  int lane = idx & 63;
  int l16 = lane & 15, quad = lane >> 4;
  int brow = (nt>>1)*256 + cs*32 + (nt&1)*16 + l16;
  int srcofs = brow*256 + kslot*32 + quad*8;
  int dst = idx*8;
  *(bf16x8*)(WhhP + dst) = LD8(Wpl + srcofs);
  *(bf16x8*)(WcP + dst)  = LD8(Wcpl + srcofs);
}

// ---------------- NT GEMM: Cb[m,n] = sum_k A[m,k]*B[n,k], M parametrized --------------
__global__ __launch_bounds__(256) void k_gemm_nt_bf(const __hip_bfloat16* __restrict__ A,
                                                    const __hip_bfloat16* __restrict__ B,
                                                    __hip_bfloat16* __restrict__ Cb, int M){
  int wave = threadIdx.x >> 6;
  int lane = threadIdx.x & 63;
  int l16 = lane & 15, quad = lane >> 4, quad8 = quad*8;
  int mBase = blockIdx.x*64 + wave*16;
  int nBase = blockIdx.y*64;
  int arow = mBase + l16; if(arow >= M) arow = M-1;
  const __hip_bfloat16* aptr = A + (size_t)arow*256 + quad8;
  float4v acc[4];
  #pragma unroll
  for(int nt=0;nt<4;nt++){ acc[nt][0]=0.f; acc[nt][1]=0.f; acc[nt][2]=0.f; acc[nt][3]=0.f; }
  for(int k0=0;k0<256;k0+=32){
    bf16x8 a = LD8(aptr + k0);
    #pragma unroll
    for(int nt=0;nt<4;nt++){
      const __hip_bfloat16* bptr = B + (size_t)(nBase + nt*16 + l16)*256 + k0 + quad8;
      acc[nt] = MFMA16(a, LD8(bptr), acc[nt]);
    }
  }
  #pragma unroll
  for(int nt=0;nt<4;nt++){
    int col = nBase + nt*16 + l16;
    #pragma unroll
    for(int r=0;r<4;r++){
      int row = mBase + quad*4 + r;
      if(row < M) Cb[(size_t)row*256 + col] = f2bf(acc[nt][r]);
    }
  }
}

// ---------------- in-place NT GEMM: P = P@B^T (LDS-staged A; row-exclusive blocks) ----
__global__ __launch_bounds__(256) void k_gemm_inplace(__hip_bfloat16* __restrict__ P,
                                                      const __hip_bfloat16* __restrict__ B){
  __shared__ __hip_bfloat16 sA[64*264];
  int tid = threadIdx.x;
  int mBase = blockIdx.x*64;
  {
    int r = tid >> 2;
    int c0 = (tid & 3)*64;
    int grow = mBase + r; if(grow >= NN) grow = NN-1;
    const __hip_bfloat16* srcp = P + (size_t)grow*256 + c0;
    #pragma unroll
    for(int j=0;j<8;j++) *(bf16x8*)(&sA[r*264 + c0 + j*8]) = LD8(srcp + j*8);
  }
  __syncthreads();
  int w = tid>>6, lane = tid&63, l16 = lane&15, quad = lane>>4, quad8 = quad*8;
  const __hip_bfloat16* arow = &sA[(w*16 + l16)*264 + quad8];
  float4v acc[16];
  #pragma unroll
  for(int nt=0;nt<16;nt++){ acc[nt][0]=0.f; acc[nt][1]=0.f; acc[nt][2]=0.f; acc[nt][3]=0.f; }
  for(int k0=0;k0<256;k0+=32){
    bf16x8 a = *(const bf16x8*)(arow + k0);
    #pragma unroll
    for(int nt=0;nt<16;nt++)
      acc[nt] = MFMA16(a, LD8(B + (size_t)(nt*16+l16)*256 + k0 + quad8), acc[nt]);
  }
  #pragma unroll
  for(int nt=0;nt<16;nt++){
    int col = nt*16 + l16;
    #pragma unroll
    for(int r=0;r<4;r++){
      int row = mBase + w*16 + quad*4 + r;
      if(row < NN) P[(size_t)row*256 + col] = f2bf(acc[nt][r]);
    }
  }
}

// ---------------- fused GAT edge phase: logits+softmax+aggregate+ELU (per node) ------
__global__ __launch_bounds__(256) void k_node_fused(const __hip_bfloat16* __restrict__ Q,
                                                    __hip_bfloat16* __restrict__ P,
                                                    const int* __restrict__ offp,
                                                    const int* __restrict__ csr_src,
                                                    const float* __restrict__ attf,
                                                    const float* __restrict__ gbiasf){
  __shared__ float slog[DEGMAX*4];
  __shared__ int ssrc[DEGMAX];
  int node = blockIdx.x;
  int tid = threadIdx.x;
  int s0 = offp[node], s1 = offp[node+1];
  if(s0 < 0) s0 = 0; if(s0 > NE) s0 = NE;
  if(s1 < s0) s1 = s0; if(s1 > NE) s1 = NE;
  int deg = s1 - s0; if(deg > DEGMAX) deg = DEGMAX;
  if(tid < deg){
    unsigned sv = (unsigned)csr_src[s0 + tid];
    ssrc[tid] = (sv < NN) ? (int)sv : 0;
  }
  __syncthreads();
  int w = tid>>6, lane = tid&63;
  for(int idx=w; idx<deg; idx+=4){
    const __hip_bfloat16* pl = Q + (size_t)ssrc[idx]*256;
    const __hip_bfloat16* pr = P + (size_t)node*256;
    float a[4];
    #pragma unroll
    for(int h=0;h<4;h++){
      float v = bf2f(pl[h*64+lane]) + bf2f(pr[h*64+lane]);
      v = (v > 0.f) ? v : 0.2f*v;
      a[h] = v * attf[h*64+lane];
    }
    #pragma unroll
    for(int h=0;h<4;h++){
      float s = a[h];
      s += __shfl_xor(s, 1, 64);
      s += __shfl_xor(s, 2, 64);
      s += __shfl_xor(s, 4, 64);
      s += __shfl_xor(s, 8, 64);
      s += __shfl_xor(s, 16, 64);
      s += __shfl_xor(s, 32, 64);
      if(lane == 0) slog[idx*4 + h] = s;
    }
  }
  __syncthreads();
  if(tid < 4){
    int h = tid;
    float m = -1e30f;
    for(int i=0;i<deg;i++) m = fmaxf(m, slog[i*4+h]);
    float den = 0.f;
    for(int i=0;i<deg;i++) den += __expf(slog[i*4+h] - m);
    float inv = (den > 0.f) ? 1.f/den : 0.f;
    for(int i=0;i<deg;i++) slog[i*4+h] = __expf(slog[i*4+h] - m)*inv;
  }
  __syncthreads();
  int d = tid, h = d>>6;
  float acc = 0.f;
  for(int i=0;i<deg;i++) acc += slog[i*4+h] * bf2f(Q[(size_t)ssrc[i]*256 + d]);
  acc += gbiasf[d];
  acc = (acc > 0.f) ? acc : (__expf(acc) - 1.f);   // ELU
  P[(size_t)node*256 + d] = f2bf(acc);
}

// ---------------- persistent LSTM: 512 threads (8 waves), 48 rows/block --------------
// r16 refuted L2 camping (4x replication = no change). New model from r13-r16 fit:
// per-block-step = ~12us fixed + ~266cyc/MFMA -> B-loads are line-scatter bound: each
// LD8 touched 16 SCATTERED 64B lines (lanes strided 512B), saturating the CU's L1/TA
// line pipeline. Fix: Whh/Wc PRE-PACKED into per-wave fragment order so every B-load
// is wave-contiguous 1024B (adjacent lines, TA-coalesced). Math unchanged.
__global__ __launch_bounds__(512, 2) void k_lstm12(const __hip_bfloat16* __restrict__ ctx,
                                                   const __hip_bfloat16* __restrict__ WcP,
                                                   const __hip_bfloat16* __restrict__ WhhP,
                                                   const float* __restrict__ u_vec,
                                                   const float* __restrict__ bc_vec,
                                                   const float* __restrict__ initwf,
                                                   const float* __restrict__ outwf,
                                                   const float* __restrict__ sc,
                                                   float* __restrict__ out){
  __shared__ __hip_bfloat16 sgx[MR*SGXP];    // 98.7KB: GX+bc, [row][gatecol]
  __shared__ __hip_bfloat16 sh[MR*264];      // 25.3KB h tile (bank-padded)
  __shared__ float spart[512];
  __shared__ float spartw[MR*8];
  __shared__ float sprev[MR];
  int tid = threadIdx.x;
  int mBase = blockIdx.x*MR;                 // 417*48 = 20016 >= NN (tail guarded)
  int cs = tid>>6, lane = tid&63, l16 = lane&15, quad = lane>>4, quad8 = quad*8;
  int phase = (blockIdx.x >> 3) & 7;
  // h0 = ctx rows
  #pragma unroll
  for(int p=0;p<2;p++){
    int r = p*32 + (tid >> 4);
    if(r < MR){
      int grow = mBase + r; if(grow >= NN) grow = NN-1;
      int c0 = (tid & 15)*16;
      const __hip_bfloat16* srcp = ctx + (size_t)grow*256 + c0;
      *(bf16x8*)(&sh[r*264 + c0])     = LD8(srcp);
      *(bf16x8*)(&sh[r*264 + c0 + 8]) = LD8(srcp + 8);
    }
  }
  __syncthreads();
  // prev0 = ctx @ init_w + init_b
  #pragma unroll
  for(int p=0;p<2;p++){
    int r = p*32 + (tid >> 4);
    int c0 = (tid & 15)*16;
    float part = 0.f;
    if(r < MR){
      #pragma unroll
      for(int j=0;j<16;j++) part += bf2f(sh[r*264 + c0 + j]) * initwf[c0 + j];
    }
    spart[tid] = part;
    __syncthreads();
    if(tid < 32 && p*32 + tid < MR){
      float s = 0.f;
      #pragma unroll
      for(int j=0;j<16;j++) s += spart[tid*16 + j];
      sprev[p*32 + tid] = s + sc[0];
    }
    __syncthreads();
  }
  // per-thread constants
  float ureg[8], owreg[2];
  #pragma unroll
  for(int g=0;g<4;g++)
    #pragma unroll
    for(int tc=0;tc<2;tc++) ureg[g*2+tc] = u_vec[g*256 + cs*32 + tc*16 + l16];
  #pragma unroll
  for(int tc=0;tc<2;tc++) owreg[tc] = outwf[cs*32 + tc*16 + l16];
  float outb = sc[1];
  // GX phase: acc = ctx@Wc^T (packed B), +bc -> sgx
  {
    float4v acc[24];
    #pragma unroll
    for(int nt=0;nt<24;nt++){ acc[nt][0]=0.f; acc[nt][1]=0.f; acc[nt][2]=0.f; acc[nt][3]=0.f; }
    #pragma unroll 2
    for(int ki=0;ki<8;ki++){
      int kidx = (ki + phase) & 7;
      int k0 = kidx*32;
      bf16x8 a0 = *(const bf16x8*)(&sh[l16*264 + k0 + quad8]);
      bf16x8 a1 = *(const bf16x8*)(&sh[(16 + l16)*264 + k0 + quad8]);
      bf16x8 a2 = *(const bf16x8*)(&sh[(32 + l16)*264 + k0 + quad8]);
      const __hip_bfloat16* bbase = WcP + (((cs<<3) + kidx)<<12) + (lane<<3);
      #pragma unroll
      for(int nt=0;nt<8;nt++){
        bf16x8 b = LD8(bbase + (nt<<9));
        acc[nt]    = MFMA16(a0, b, acc[nt]);
        acc[8+nt]  = MFMA16(a1, b, acc[8+nt]);
        acc[16+nt] = MFMA16(a2, b, acc[16+nt]);
      }
    }
    #pragma unroll
    for(int rt=0;rt<3;rt++)
      #pragma unroll
      for(int nt=0;nt<8;nt++){
        int gc = (nt>>1)*256 + cs*32 + (nt&1)*16 + l16;
        float bcv = bc_vec[gc];
        #pragma unroll
        for(int r=0;r<4;r++)
          sgx[(rt*16 + quad*4 + r)*SGXP + gc] = f2bf(acc[rt*8+nt][r] + bcv);
      }
  }
  __syncthreads();
  float creg[24];
  #pragma unroll
  for(int i=0;i<24;i++) creg[i] = 0.f;
  for(int step=0; step<TOUT; step++){
    // (a) gates GEMM with packed, wave-contiguous B loads
    float4v acc[24];
    #pragma unroll
    for(int nt=0;nt<24;nt++){ acc[nt][0]=0.f; acc[nt][1]=0.f; acc[nt][2]=0.f; acc[nt][3]=0.f; }
    #pragma unroll 2
    for(int ki=0;ki<8;ki++){
      int kidx = (ki + phase) & 7;
      int k0 = kidx*32;
      bf16x8 a0 = *(const bf16x8*)(&sh[l16*264 + k0 + quad8]);
      bf16x8 a1 = *(const bf16x8*)(&sh[(16 + l16)*264 + k0 + quad8]);
      bf16x8 a2 = *(const bf16x8*)(&sh[(32 + l16)*264 + k0 + quad8]);
      const __hip_bfloat16* bbase = WhhP + (((cs<<3) + kidx)<<12) + (lane<<3);
      #pragma unroll
      for(int nt=0;nt<8;nt++){
        bf16x8 b = LD8(bbase + (nt<<9));
        acc[nt]    = MFMA16(a0, b, acc[nt]);
        acc[8+nt]  = MFMA16(a1, b, acc[8+nt]);
        acc[16+nt] = MFMA16(a2, b, acc[16+nt]);
      }
    }
    __syncthreads();   // S1
    // (b) in-register activation + h write + out-projection partials
    float hsum[12];
    #pragma unroll
    for(int i=0;i<12;i++) hsum[i] = 0.f;
    #pragma unroll
    for(int rt=0;rt<3;rt++)
      #pragma unroll
      for(int tc=0;tc<2;tc++){
        int col = cs*32 + tc*16 + l16;
        #pragma unroll
        for(int r=0;r<4;r++){
          int row = rt*16 + quad*4 + r;
          float p = sprev[row];
          float g0 = acc[rt*8 + tc][r]     + bf2f(sgx[row*SGXP + col])       + p*ureg[tc];
          float g1 = acc[rt*8 + 2 + tc][r] + bf2f(sgx[row*SGXP + 256 + col]) + p*ureg[2+tc];
          float g2 = acc[rt*8 + 4 + tc][r] + bf2f(sgx[row*SGXP + 512 + col]) + p*ureg[4+tc];
          float g3 = acc[rt*8 + 6 + tc][r] + bf2f(sgx[row*SGXP + 768 + col]) + p*ureg[6+tc];
          float iv = sigmoidf_(g0), fv = sigmoidf_(g1);
          float gv = tanhf_(g2),    ov = sigmoidf_(g3);
          float cn = fv*creg[rt*8 + tc*4 + r] + iv*gv;
          creg[rt*8 + tc*4 + r] = cn;
          float hn = ov * tanhf_(cn);
          sh[row*264 + col] = f2bf(hn);
          hsum[rt*4 + r] += hn * owreg[tc];
        }
      }
    #pragma unroll
    for(int rr=0;rr<12;rr++){
      hsum[rr] += __shfl_xor(hsum[rr], 1, 64);
      hsum[rr] += __shfl_xor(hsum[rr], 2, 64);
      hsum[rr] += __shfl_xor(hsum[rr], 4, 64);
      hsum[rr] += __shfl_xor(hsum[rr], 8, 64);
    }
    if(l16 == 0){
      #pragma unroll
      for(int rt=0;rt<3;rt++)
        #pragma unroll
        for(int r=0;r<4;r++)
          spartw[(rt*16 + quad*4 + r)*8 + cs] = hsum[rt*4 + r];
    }
    __syncthreads();   // S2
    if(tid < MR){
      float s = outb;
      #pragma unroll
      for(int c=0;c<8;c++) s += spartw[tid*8 + c];
      sprev[tid] = s;
      int row = mBase + tid;
      if(row < NN) out[(size_t)row*TOUT + step] = s;
    }
  }
}

// ---------------- launch ----------------
extern "C" void kernel_launch(void* const* d_in, const int* in_sizes, int n_in,
                              void* d_out, int out_size, void* d_ws, size_t ws_size,
                              hipStream_t stream){
  const void* x      = d_in[0];
  const int*  ei     = (const int*)d_in[1];
  const void* w_src  = d_in[2];
  const void* w_dst  = d_in[3];
  const void* att    = d_in[4];
  const void* gbias  = d_in[5];
  const void* mlp_w  = d_in[6];
  const void* mlp_b  = d_in[7];
  const void* w_ih   = d_in[8];
  const void* w_hh   = d_in[9];
  const void* b_ih   = d_in[10];
  const void* b_hh   = d_in[11];
  const void* init_w = d_in[12];
  const void* init_b = d_in[13];
  const void* out_w  = d_in[14];
  const void* out_b  = d_in[15];
  float* out = (float*)d_out;
  const int* srcp = ei;
  const int* dstp = ei + NE;
  (void)in_sizes; (void)n_in;

  char* ws = (char*)d_ws;
  size_t off = 0;
  auto alloc = [&](size_t bytes)->void*{
    void* p = ws + off;
    off += (bytes + 255) & ~(size_t)255;
    return p;
  };
  __hip_bfloat16* P = (__hip_bfloat16*)alloc((size_t)NN*256*2);  // x -> xr -> layer out -> ctx
  __hip_bfloat16* Q = (__hip_bfloat16*)alloc((size_t)NN*256*2);  // xl per layer
  int* deg      = (int*)alloc((size_t)NN*4);
  int* offp     = (int*)alloc((size_t)(NN+1)*4);
  int* cursor   = (int*)alloc((size_t)NN*4);
  int* csr_src  = (int*)alloc((size_t)NE*4);
  __hip_bfloat16* wsrcT   = (__hip_bfloat16*)alloc((size_t)131072*2);
  __hip_bfloat16* wdstT   = (__hip_bfloat16*)alloc((size_t)131072*2);
  __hip_bfloat16* whh_pl  = (__hip_bfloat16*)alloc((size_t)262144*2);
  __hip_bfloat16* Wc_pl   = (__hip_bfloat16*)alloc((size_t)262144*2);
  __hip_bfloat16* WhhP    = (__hip_bfloat16*)alloc((size_t)262144*2);
  __hip_bfloat16* WcP     = (__hip_bfloat16*)alloc((size_t)262144*2);
  __hip_bfloat16* wihb    = (__hip_bfloat16*)alloc((size_t)262144*2);
  __hip_bfloat16* mlpT    = (__hip_bfloat16*)alloc((size_t)65536*2);
  float* u_vec  = (float*)alloc(1024*4);
  float* bc_vec = (float*)alloc(1024*4);
  float* attf   = (float*)alloc(512*4);
  float* gbiasf = (float*)alloc(512*4);
  float* initwf = (float*)alloc(256*4);
  float* outwf  = (float*)alloc(256*4);
  float* sc     = (float*)alloc(2*4);
  int*   flag   = (int*)alloc(4);
  // total ~27 MB

  if(off > ws_size){
    k_fail<<<(out_size + 255)/256, 256, 0, stream>>>(out, out_size);
    return;
  }

  // dtype detect + CSR + prep
  k_detect<<<1, 256, 0, stream>>>(x, flag);
  hipMemsetAsync(deg, 0, (size_t)NN*4, stream);
  hipMemsetAsync(csr_src, 0xFF, (size_t)NE*4, stream);
  k_count<<<NE/256, 256, 0, stream>>>(dstp, deg);
  k_scan<<<1, 256, 0, stream>>>(deg, offp, cursor);
  k_fill<<<NE/256, 256, 0, stream>>>(srcp, dstp, cursor, csr_src);
  k_cvt_x<<<NN, 256, 0, stream>>>(x, flag, P);
  k_prep<<<1024, 256, 0, stream>>>(w_src, w_dst, w_hh, flag, wsrcT, wdstT, whh_pl);
  k_cvt2<<<1024, 256, 0, stream>>>(w_ih, mlp_w, flag, wihb, mlpT);
  {
    dim3 gwc(16, 4);
    k_gemm_nt_bf<<<gwc, 256, 0, stream>>>(wihb, mlpT, Wc_pl, 1024);   // Wc = Wih @ mlpT^T
  }
  k_pack<<<128, 256, 0, stream>>>(whh_pl, Wc_pl, WhhP, WcP);
  k_prep_ub<<<1024, 256, 0, stream>>>(w_ih, mlp_w, mlp_b, b_ih, b_hh, flag, u_vec, bc_vec);
  k_prep_small<<<2, 256, 0, stream>>>(att, gbias, init_w, init_b, out_w, out_b, flag,
                                      attf, gbiasf, initwf, outwf, sc);

  // GAT layers: Q = P@Wsrc^T (xl); P = P@Wdst^T in-place (xr); fused edge phase -> P
  dim3 g64(313, 4);
  for(int l=0;l<2;l++){
    k_gemm_nt_bf<<<g64, 256, 0, stream>>>(P, wsrcT + l*65536, Q, NN);
    k_gemm_inplace<<<313, 256, 0, stream>>>(P, wdstT + l*65536);
    k_node_fused<<<NN, 256, 0, stream>>>(Q, P, offp, csr_src, attf + l*256, gbiasf + l*256);
  }

  // persistent LSTM decoder: fragment-packed weights, wave-contiguous B loads
  k_lstm12<<<NBLK, 512, 0, stream>>>(P, WcP, WhhP, u_vec, bc_vec, initwf, outwf, sc, out);
}